// Round 9
// baseline (491.912 us; speedup 1.0000x reference)
//
#include <hip/hip_runtime.h>
#include <hip/hip_bf16.h>

// AttentionCircuit round 17 (= round 14 base + Q/K-fused GEMM):
//  - qkv_gemm split: qk_gemm (512 thr, 2 wave-groups sharing ONE staged
//    B-tile: group0->Q via wq, group1->K via wk; 2x MFMA per staged byte,
//    RT q-half fetched once, 24 waves/CU) + v_gemm (round-12 structure,
//    which=2 only). Per-wave VGPR unchanged (~120) - no spill cliff.
//    LDS qk: hs 34816 (aliased by wslq+wslk after hreg hoist) + Bs 16384
//    = 51200 B -> 3 blocks/CU.
//  - rounds 13/15/16 qkv restructures all reverted (each regressed).
//  - attn qb swizzle, Qs-less attn, round-8 softmax, r14 pk_mul retained.

namespace {
constexpr int kS = 2048;
constexpr int kD = 1024;
}

typedef unsigned short u16;
typedef __attribute__((ext_vector_type(2))) float f32x2;
typedef __attribute__((ext_vector_type(4))) float f32x4;
typedef __attribute__((ext_vector_type(8))) short s8v;   // 8 bf16 = 4 VGPRs

union FragU { s8v s; unsigned u[4]; };
union F4U { f32x4 v; f32x2 p[2]; };

__device__ __forceinline__ u16 f2bf_bits(float f) {
  union { float f; unsigned u; } cv; cv.f = f;
  unsigned u = cv.u;
  unsigned r = u + 0x7fffu + ((u >> 16) & 1u);   // RNE
  return (u16)(r >> 16);
}
__device__ __forceinline__ float bf2f(u16 b) {
  union { unsigned u; float f; } cv; cv.u = ((unsigned)b) << 16; return cv.f;
}
__device__ __forceinline__ unsigned pk_bf16(float a, float b) {
  __hip_bfloat162 h = __float22bfloat162_rn(make_float2(a, b));
  union { __hip_bfloat162 h; unsigned u; } cv; cv.h = h; return cv.u;
}
// async global->LDS, 16B per lane; LDS dest = wave-uniform base + lane*16
__device__ __forceinline__ void gl_lds16(const void* g, void* l) {
  __builtin_amdgcn_global_load_lds(
      (const __attribute__((address_space(1))) unsigned int*)g,
      (__attribute__((address_space(3))) unsigned int*)l, 16, 0, 0);
}

// ---------------------------------------------------------------------------
// conv_x: x fp32 -> xb bf16 (8 elems/thread).  conv_wo: same for W_O.
// ---------------------------------------------------------------------------
__global__ __launch_bounds__(256) void conv_x(const float* __restrict__ x,
                                              u16* __restrict__ xb) {
  int idx = blockIdx.x * 256 + threadIdx.x;
  float4 v0 = ((const float4*)x)[idx * 2];
  float4 v1 = ((const float4*)x)[idx * 2 + 1];
  uint4 o = { pk_bf16(v0.x, v0.y), pk_bf16(v0.z, v0.w),
              pk_bf16(v1.x, v1.y), pk_bf16(v1.z, v1.w) };
  ((uint4*)xb)[idx] = o;
}

// ---------------------------------------------------------------------------
// T1: FT[n*64+r][d] = f[n][d][r]  (bf16)  — B^T layout for G-GEMM.
// ---------------------------------------------------------------------------
__global__ __launch_bounds__(256) void t1_kernel(const float* __restrict__ f,
                                                 u16* __restrict__ FT) {
  __shared__ float Tt[64 * 132];
  const int tid = threadIdx.x;
  const int d0 = blockIdx.x * 128;
  const int n  = blockIdx.y;
#pragma unroll
  for (int e = 0; e < 8; ++e) {
    int flat = tid + e * 256;            // 0..2047
    int dd = flat >> 4, r4 = (flat & 15) * 4;
    float4 v = *(const float4*)&f[((size_t)n * kD + d0 + dd) * 64 + r4];
    Tt[(r4 + 0) * 132 + dd] = v.x;
    Tt[(r4 + 1) * 132 + dd] = v.y;
    Tt[(r4 + 2) * 132 + dd] = v.z;
    Tt[(r4 + 3) * 132 + dd] = v.w;
  }
  __syncthreads();
#pragma unroll
  for (int e = 0; e < 4; ++e) {
    int flat = tid + e * 256;            // 0..1023
    int r = flat >> 4, dq = (flat & 15) * 8;
    const float* p = &Tt[r * 132 + dq];
    uint4 o = { pk_bf16(p[0], p[1]), pk_bf16(p[2], p[3]),
                pk_bf16(p[4], p[5]), pk_bf16(p[6], p[7]) };
    *(uint4*)&FT[((size_t)n * 64 + r) * kD + d0 + dq] = o;
  }
}

// ---------------------------------------------------------------------------
// T2: RT[d][n*64+r] = r_neurons[n][r][d] (bf16) — B^T layout for QKV GEMM.
// ---------------------------------------------------------------------------
__global__ __launch_bounds__(256) void t2_kernel(const float* __restrict__ rn,
                                                 u16* __restrict__ RT) {
  __shared__ float Tt[128 * 68];
  const int tid = threadIdx.x;
  const int d0 = blockIdx.x * 128;
  const int n  = blockIdx.y;             // 0..63
#pragma unroll
  for (int e = 0; e < 8; ++e) {
    int flat = tid + e * 256;            // 0..2047
    int r = flat >> 5, d4 = (flat & 31) * 4;
    float4 v = *(const float4*)&rn[((size_t)n * 64 + r) * kD + d0 + d4];
    Tt[(d4 + 0) * 68 + r] = v.x;
    Tt[(d4 + 1) * 68 + r] = v.y;
    Tt[(d4 + 2) * 68 + r] = v.z;
    Tt[(d4 + 3) * 68 + r] = v.w;
  }
  __syncthreads();
#pragma unroll
  for (int e = 0; e < 4; ++e) {
    int flat = tid + e * 256;            // 0..1023
    int dd = flat >> 3, rq = (flat & 7) * 8;
    const float* p = &Tt[dd * 68 + rq];
    uint4 o = { pk_bf16(p[0], p[1]), pk_bf16(p[2], p[3]),
                pk_bf16(p[4], p[5]), pk_bf16(p[6], p[7]) };
    *(uint4*)&RT[((size_t)(d0 + dd)) * 4096 + n * 64 + rq] = o;
  }
}

// ---------------------------------------------------------------------------
// G-GEMM: G[t][g] = sum_d xb[t,d] * FT[g][d].  128x128 tile, BK=64.
// Unpadded swizzled LDS (row r unit u at u^(r&7)), global_load_lds staging.
// ---------------------------------------------------------------------------
__global__ __launch_bounds__(256) void g_gemm(const u16* __restrict__ xb,
                                              const u16* __restrict__ FT,
                                              u16* __restrict__ G) {
  __shared__ short As[128 * 64];
  __shared__ short Bs[128 * 64];
  const int tid = threadIdx.x;
  const int lane = tid & 63, wid = tid >> 6;
  const int wm = wid & 1, wn = wid >> 1;
  const int quad = lane >> 4, l15 = lane & 15;
  const int cT = blockIdx.x * 128;
  const int tok0 = blockIdx.y * 128;

  f32x4 acc[4][4];
#pragma unroll
  for (int mt = 0; mt < 4; ++mt)
#pragma unroll
    for (int nt = 0; nt < 4; ++nt) acc[mt][nt] = {0.f, 0.f, 0.f, 0.f};

#pragma unroll 1
  for (int d0 = 0; d0 < kD; d0 += 64) {
    __syncthreads();
#pragma unroll
    for (int e = 0; e < 4; ++e) {                 // A: 128x64, DMA swizzled
      int flat = tid + e * 256;                   // 0..1023 (16B units)
      int r = flat >> 3, u = (flat & 7) ^ (r & 7);
      gl_lds16(&xb[(size_t)(tok0 + r) * kD + d0 + u * 8], &As[flat * 8]);
    }
#pragma unroll
    for (int e = 0; e < 4; ++e) {                 // B: 128x64, DMA swizzled
      int flat = tid + e * 256;
      int r = flat >> 3, u = (flat & 7) ^ (r & 7);
      gl_lds16(&FT[(size_t)(cT + r) * kD + d0 + u * 8], &Bs[flat * 8]);
    }
    __syncthreads();
    s8v a0[4], a1[4], b0[4], b1[4];
#pragma unroll
    for (int mt = 0; mt < 4; ++mt) {
      int r = wm * 64 + mt * 16 + l15;
      a0[mt] = *(const s8v*)&As[r * 64 + ((quad) ^ (r & 7)) * 8];
      a1[mt] = *(const s8v*)&As[r * 64 + ((4 + quad) ^ (r & 7)) * 8];
    }
#pragma unroll
    for (int nt = 0; nt < 4; ++nt) {
      int r = wn * 64 + nt * 16 + l15;
      b0[nt] = *(const s8v*)&Bs[r * 64 + ((quad) ^ (r & 7)) * 8];
      b1[nt] = *(const s8v*)&Bs[r * 64 + ((4 + quad) ^ (r & 7)) * 8];
    }
#pragma unroll
    for (int mt = 0; mt < 4; ++mt)
#pragma unroll
      for (int nt = 0; nt < 4; ++nt) {
        acc[mt][nt] = __builtin_amdgcn_mfma_f32_16x16x32_bf16(
            a0[mt], b0[nt], acc[mt][nt], 0, 0, 0);
        acc[mt][nt] = __builtin_amdgcn_mfma_f32_16x16x32_bf16(
            a1[mt], b1[nt], acc[mt][nt], 0, 0, 0);
      }
  }
#pragma unroll
  for (int mt = 0; mt < 4; ++mt)
#pragma unroll
    for (int nt = 0; nt < 4; ++nt) {
      int col = cT + wn * 64 + nt * 16 + l15;
      int rbase = tok0 + wm * 64 + mt * 16 + quad * 4;
#pragma unroll
      for (int i = 0; i < 4; ++i)
        G[(size_t)(rbase + i) * 4096 + col] = f2bf_bits(acc[mt][nt][i]);
    }
}

// ---------------------------------------------------------------------------
// reduce_h: h_qk[t][r] = sum_n fqk_w[t][n]*G[t][n*64+r]; h_v from cols 2048+.
// ---------------------------------------------------------------------------
__global__ __launch_bounds__(256) void reduce_h(const u16* __restrict__ G,
                                                const float* __restrict__ fqk_w,
                                                const float* __restrict__ fv_w,
                                                float* __restrict__ h_qk,
                                                float* __restrict__ h_v) {
  int idx = blockIdx.x * 256 + threadIdx.x;    // 0..131071
  int t = idx >> 4, r4 = (idx & 15) * 4;
  float4 aq = {0.f, 0.f, 0.f, 0.f}, av = {0.f, 0.f, 0.f, 0.f};
  const u16* gq = &G[(size_t)t * 4096 + r4];
  const u16* gv = gq + 2048;
#pragma unroll 4
  for (int n = 0; n < 32; ++n) {
    float wa = fqk_w[t * 32 + n];
    float wb = fv_w[t * 32 + n];
    ushort4 g1 = *(const ushort4*)&gq[n * 64];
    ushort4 g2 = *(const ushort4*)&gv[n * 64];
    aq.x += wa * bf2f(g1.x); aq.y += wa * bf2f(g1.y);
    aq.z += wa * bf2f(g1.z); aq.w += wa * bf2f(g1.w);
    av.x += wb * bf2f(g2.x); av.y += wb * bf2f(g2.y);
    av.z += wb * bf2f(g2.z); av.w += wb * bf2f(g2.w);
  }
  *(float4*)&h_qk[t * 64 + r4] = aq;
  *(float4*)&h_v[t * 64 + r4] = av;
}

// ---------------------------------------------------------------------------
// QK-GEMM (fused): 512 threads, 2 wave-groups over one staged B tile.
//   group 0 (waves 0-3): Q[t][d] = sum_g (wq[t,n]*h_qk[t,r]) * RT[d][g]
//   group 1 (waves 4-7): K[t][d] = sum_g (wk[t,n]*h_qk[t,r]) * RT[d][g]
// LDS: hs 34816 (after hreg hoist re-used for wslq+wslk, 33792) + Bs 16384
// = 51200 B. Round-12 2-barrier loop structure (verified).
// ---------------------------------------------------------------------------
__global__ __launch_bounds__(512) void qk_gemm(
    const float* __restrict__ h_qk, const float* __restrict__ wq,
    const float* __restrict__ wk, const u16* __restrict__ RT,
    u16* __restrict__ Qb, u16* __restrict__ Kb) {
  __shared__ float hs[128 * 68];                 // 34816 B; -> wslq|wslk
  __shared__ short Bs[128 * 64];                 // 16384 B
  float* wslq = hs;                              // 128*33 = 16896 B
  float* wslk = hs + 128 * 33;                   // 16896 B (33792 <= 34816)
  const int tid = threadIdx.x;
  const int lane = tid & 63, wid = tid >> 6;     // 0..7
  const int grp = wid >> 2, w2 = wid & 3;
  const int wm = w2 & 1, wn = w2 >> 1;
  const int quad = lane >> 4, l15 = lane & 15;
  const int dT = blockIdx.x * 128;
  const int tok0 = blockIdx.y * 128;

#pragma unroll
  for (int e = 0; e < 4; ++e) {                  // h tile: 128x64 fp32
    int flat = tid + e * 512;                    // 0..2047 (float4 units)
    int row = flat >> 4, rq = (flat & 15) * 4;
    *(float4*)&hs[row * 68 + rq] =
        *(const float4*)&h_qk[(size_t)(tok0 + row) * 64 + rq];
  }
  __syncthreads();

  f32x4 hreg[4][4];
#pragma unroll
  for (int mt = 0; mt < 4; ++mt) {
    const float* hp = &hs[(wm * 64 + mt * 16 + l15) * 68 + quad * 8];
    hreg[mt][0] = *(const f32x4*)hp;
    hreg[mt][1] = *(const f32x4*)(hp + 4);
    hreg[mt][2] = *(const f32x4*)(hp + 32);
    hreg[mt][3] = *(const f32x4*)(hp + 36);
  }
  __syncthreads();                               // hs reads done -> re-use

#pragma unroll
  for (int e = 0; e < 8; ++e) {                  // both weight tiles 128x32
    int flat = tid + e * 512;                    // 0..4095
    int row = flat >> 5, nn = flat & 31;
    wslq[row * 33 + nn] = wq[(size_t)(tok0 + row) * 32 + nn];
    wslk[row * 33 + nn] = wk[(size_t)(tok0 + row) * 32 + nn];
  }
  // visibility of wsl writes is sealed by the loop-top barrier below

  const float* __restrict__ wsl = grp ? wslk : wslq;
  u16* __restrict__ Ob = grp ? Kb : Qb;

  f32x4 acc[4][4];
#pragma unroll
  for (int mt = 0; mt < 4; ++mt)
#pragma unroll
    for (int nt = 0; nt < 4; ++nt) acc[mt][nt] = {0.f, 0.f, 0.f, 0.f};

#pragma unroll 1
  for (int n = 0; n < 32; ++n) {
    __syncthreads();                             // Bs reads done / wsl ready
#pragma unroll
    for (int e = 0; e < 2; ++e) {                // B: 128x64, DMA swizzled
      int flat = tid + e * 512;                  // 0..1023 (16B units)
      int r = flat >> 3, u = (flat & 7) ^ (r & 7);
      gl_lds16(&RT[(size_t)(dT + r) * 4096 + n * 64 + u * 8],
               &Bs[flat * 8]);
    }
    __syncthreads();
    s8v a0[4], a1[4], b0[4], b1[4];
#pragma unroll
    for (int nt = 0; nt < 4; ++nt) {
      int r = wn * 64 + nt * 16 + l15;
      b0[nt] = *(const s8v*)&Bs[r * 64 + ((quad) ^ (r & 7)) * 8];
      b1[nt] = *(const s8v*)&Bs[r * 64 + ((4 + quad) ^ (r & 7)) * 8];
    }
#pragma unroll
    for (int mt = 0; mt < 4; ++mt) {
      float wv_ = wsl[(wm * 64 + mt * 16 + l15) * 33 + n];
      f32x2 w2v = {wv_, wv_};
      F4U h0, h1, h2, h3;
      h0.v = hreg[mt][0]; h1.v = hreg[mt][1];
      h2.v = hreg[mt][2]; h3.v = hreg[mt][3];
      f32x2 a00 = w2v * h0.p[0], a01 = w2v * h0.p[1];
      f32x2 a10 = w2v * h1.p[0], a11 = w2v * h1.p[1];
      f32x2 a20 = w2v * h2.p[0], a21 = w2v * h2.p[1];
      f32x2 a30 = w2v * h3.p[0], a31 = w2v * h3.p[1];
      FragU fa, fb;
      fa.u[0] = pk_bf16(a00[0], a00[1]);
      fa.u[1] = pk_bf16(a01[0], a01[1]);
      fa.u[2] = pk_bf16(a10[0], a10[1]);
      fa.u[3] = pk_bf16(a11[0], a11[1]);
      a0[mt] = fa.s;
      fb.u[0] = pk_bf16(a20[0], a20[1]);
      fb.u[1] = pk_bf16(a21[0], a21[1]);
      fb.u[2] = pk_bf16(a30[0], a30[1]);
      fb.u[3] = pk_bf16(a31[0], a31[1]);
      a1[mt] = fb.s;
    }
#pragma unroll
    for (int mt = 0; mt < 4; ++mt)
#pragma unroll
      for (int nt = 0; nt < 4; ++nt) {
        acc[mt][nt] = __builtin_amdgcn_mfma_f32_16x16x32_bf16(
            a0[mt], b0[nt], acc[mt][nt], 0, 0, 0);
        acc[mt][nt] = __builtin_amdgcn_mfma_f32_16x16x32_bf16(
            a1[mt], b1[nt], acc[mt][nt], 0, 0, 0);
      }
  }

#pragma unroll
  for (int mt = 0; mt < 4; ++mt)
#pragma unroll
    for (int nt = 0; nt < 4; ++nt) {
      int col = dT + wn * 64 + nt * 16 + l15;
      int rbase = tok0 + wm * 64 + mt * 16 + quad * 4;
#pragma unroll
      for (int i = 0; i < 4; ++i)
        Ob[(size_t)(rbase + i) * kD + col] = f2bf_bits(acc[mt][nt][i]);
    }
}

// ---------------------------------------------------------------------------
// V-GEMM: round-12 qkv structure, which=2 only (VTg output).
// ---------------------------------------------------------------------------
__global__ __launch_bounds__(256) void v_gemm(
    const float* __restrict__ h_v, const float* __restrict__ wv,
    const u16* __restrict__ RT, u16* __restrict__ VTg) {
  __shared__ float hs[128 * 68];                 // aliased by Bs after hoist
  __shared__ float wsl[128 * 33];
  short* Bs = (short*)hs;                        // 128*64*2 = 16 KB
  const int tid = threadIdx.x;
  const int lane = tid & 63, wid = tid >> 6;
  const int wm = wid & 1, wn = wid >> 1;
  const int quad = lane >> 4, l15 = lane & 15;
  const int dT = blockIdx.x * 128;
  const int tok0 = blockIdx.y * 128;

#pragma unroll
  for (int e = 0; e < 8; ++e) {                  // h tile: 128x64 fp32
    int flat = tid + e * 256;                    // 0..2047 (float4 units)
    int row = flat >> 4, rq = (flat & 15) * 4;
    *(float4*)&hs[row * 68 + rq] =
        *(const float4*)&h_v[(size_t)(tok0 + row) * 64 + rq];
  }
#pragma unroll
  for (int e = 0; e < 16; ++e) {                 // w tile: 128x32 fp32
    int flat = tid + e * 256;                    // 0..4095
    int row = flat >> 5, nn = flat & 31;
    wsl[row * 33 + nn] = wv[(size_t)(tok0 + row) * 32 + nn];
  }
  __syncthreads();

  f32x4 hreg[4][4];
#pragma unroll
  for (int mt = 0; mt < 4; ++mt) {
    const float* hp = &hs[(wm * 64 + mt * 16 + l15) * 68 + quad * 8];
    hreg[mt][0] = *(const f32x4*)hp;
    hreg[mt][1] = *(const f32x4*)(hp + 4);
    hreg[mt][2] = *(const f32x4*)(hp + 32);
    hreg[mt][3] = *(const f32x4*)(hp + 36);
  }

  f32x4 acc[4][4];
#pragma unroll
  for (int mt = 0; mt < 4; ++mt)
#pragma unroll
    for (int nt = 0; nt < 4; ++nt) acc[mt][nt] = {0.f, 0.f, 0.f, 0.f};

#pragma unroll 1
  for (int n = 0; n < 32; ++n) {
    __syncthreads();                             // hs reads done / prev iter
#pragma unroll
    for (int e = 0; e < 4; ++e) {                // B: 128x64, DMA swizzled
      int flat = tid + e * 256;                  // 0..1023 (16B units)
      int r = flat >> 3, u = (flat & 7) ^ (r & 7);
      gl_lds16(&RT[(size_t)(dT + r) * 4096 + 2048 + n * 64 + u * 8],
               &Bs[flat * 8]);
    }
    __syncthreads();
    s8v a0[4], a1[4], b0[4], b1[4];
#pragma unroll
    for (int mt = 0; mt < 4; ++mt) {
      float wv_ = wsl[(wm * 64 + mt * 16 + l15) * 33 + n];
      f32x2 w2v = {wv_, wv_};
      F4U h0, h1, h2, h3;
      h0.v = hreg[mt][0]; h1.v = hreg[mt][1];
      h2.v = hreg[mt][2]; h3.v = hreg[mt][3];
      f32x2 a00 = w2v * h0.p[0], a01 = w2v * h0.p[1];
      f32x2 a10 = w2v * h1.p[0], a11 = w2v * h1.p[1];
      f32x2 a20 = w2v * h2.p[0], a21 = w2v * h2.p[1];
      f32x2 a30 = w2v * h3.p[0], a31 = w2v * h3.p[1];
      FragU fa, fb;
      fa.u[0] = pk_bf16(a00[0], a00[1]);
      fa.u[1] = pk_bf16(a01[0], a01[1]);
      fa.u[2] = pk_bf16(a10[0], a10[1]);
      fa.u[3] = pk_bf16(a11[0], a11[1]);
      a0[mt] = fa.s;
      fb.u[0] = pk_bf16(a20[0], a20[1]);
      fb.u[1] = pk_bf16(a21[0], a21[1]);
      fb.u[2] = pk_bf16(a30[0], a30[1]);
      fb.u[3] = pk_bf16(a31[0], a31[1]);
      a1[mt] = fb.s;
    }
#pragma unroll
    for (int nt = 0; nt < 4; ++nt) {
      int r = wn * 64 + nt * 16 + l15;
      b0[nt] = *(const s8v*)&Bs[r * 64 + ((quad) ^ (r & 7)) * 8];
      b1[nt] = *(const s8v*)&Bs[r * 64 + ((4 + quad) ^ (r & 7)) * 8];
    }
#pragma unroll
    for (int mt = 0; mt < 4; ++mt)
#pragma unroll
      for (int nt = 0; nt < 4; ++nt) {
        acc[mt][nt] = __builtin_amdgcn_mfma_f32_16x16x32_bf16(
            a0[mt], b0[nt], acc[mt][nt], 0, 0, 0);
        acc[mt][nt] = __builtin_amdgcn_mfma_f32_16x16x32_bf16(
            a1[mt], b1[nt], acc[mt][nt], 0, 0, 0);
      }
  }

#pragma unroll
  for (int mt = 0; mt < 4; ++mt)
#pragma unroll
    for (int nt = 0; nt < 4; ++nt) {
      int d = dT + wn * 64 + nt * 16 + l15;
      int hh = d >> 6, dl = d & 63;
      int t = tok0 + wm * 64 + mt * 16 + quad * 4;     // 4 consecutive tokens
      int bb = t >> 11, sl = t & 2047;
      ushort4 u = { f2bf_bits(acc[mt][nt][0]), f2bf_bits(acc[mt][nt][1]),
                    f2bf_bits(acc[mt][nt][2]), f2bf_bits(acc[mt][nt][3]) };
      *(ushort4*)&VTg[(((size_t)bb * 16 + hh) * 64 + dl) * kS + sl] = u;
    }
}

// ---------------------------------------------------------------------------
// conv_wo: W_O fp32 -> bf16 (runs after v_gemm, into dead RT region).
// ---------------------------------------------------------------------------
__global__ __launch_bounds__(256) void conv_wo(const float* __restrict__ WO,
                                               u16* __restrict__ wob) {
  int idx = blockIdx.x * 256 + threadIdx.x;
  float4 v0 = ((const float4*)WO)[idx * 2];
  float4 v1 = ((const float4*)WO)[idx * 2 + 1];
  uint4 o = { pk_bf16(v0.x, v0.y), pk_bf16(v0.z, v0.w),
              pk_bf16(v1.x, v1.y), pk_bf16(v1.z, v1.w) };
  ((uint4*)wob)[idx] = o;
}

// ---------------------------------------------------------------------------
// Flash attention, transposed-score MFMA.
// Round 12 config: qb swizzle, no Qs LDS tile, round-8 softmax.
// ---------------------------------------------------------------------------
__global__ __launch_bounds__(512) void attn_mfma(
    const u16* __restrict__ Qb, const u16* __restrict__ Kb,
    const u16* __restrict__ VTg, u16* __restrict__ AOb)
{
  __shared__ short Ks[64 * 72];       // [k-tok][d]
  __shared__ short VTs[64 * 72];      // [d][k-tok]
  __shared__ short Ps[8][16 * 72];    // per-wave P strip [q-local][k-tok]
  const int tid = threadIdx.x;
  const int lane = tid & 63, w = tid >> 6;       // w 0..7
  const int quad = lane >> 4, l15 = lane & 15;
  const int qb = (blockIdx.x + blockIdx.y + 4 * blockIdx.z) & 15;
  const int hh = blockIdx.y, b = blockIdx.z;
  const int dh = hh * 64;
  const size_t qrow0 = (size_t)b * kS + (size_t)qb * 128;
  const int ktmax = qb * 2 + 1;
  const u16* __restrict__ vbase = VTg + ((size_t)(b * 16 + hh) * 64) * kS;

  const int prow = tid >> 3;                     // 0..63
  const int pd8  = (tid & 7) * 8;                // 16B staging mapping

  *(uint4*)&Ks[prow * 72 + pd8] =
      *(const uint4*)&Kb[((size_t)b * kS + prow) * kD + dh + pd8];
  *(uint4*)&VTs[prow * 72 + pd8] =
      *(const uint4*)&vbase[(size_t)prow * kS + pd8];

  // Q fragments: one-time per-wave direct global load
  const size_t qrow = qrow0 + w * 16 + l15;
  s8v bq0 = *(const s8v*)&Qb[qrow * kD + dh + quad * 8];
  s8v bq1 = *(const s8v*)&Qb[qrow * kD + dh + 32 + quad * 8];
  __syncthreads();

  const int q_g = qb * 128 + w * 16 + l15;
  const int qmax_w = qb * 128 + w * 16 + 15;
  float m = -INFINITY, l = 0.f;
  f32x4 O[4];
#pragma unroll
  for (int dt = 0; dt < 4; ++dt) O[dt] = {0.f, 0.f, 0.f, 0.f};

#pragma unroll 1
  for (int kt = 0; kt <= ktmax; ++kt) {
    uint4 pk, pv;
    if (kt < ktmax) {
      const size_t krn = (size_t)b * kS + (size_t)(kt + 1) * 64;
      pk = *(const uint4*)&Kb[(krn + prow) * kD + dh + pd8];
      pv = *(const uint4*)&vbase[(size_t)prow * kS + (kt + 1) * 64 + pd8];
    }

    if (kt * 64 <= qmax_w) {
      f32x4 st[4];
#pragma unroll
      for (int nt = 0; nt < 4; ++nt) {
        const short* p = &Ks[(nt * 16 + l15) * 72 + quad * 8];
        s8v ak0 = *(const s8v*)p;
        s8v ak1 = *(const s8v*)(p + 32);
        f32x4 z = {0.f, 0.f, 0.f, 0.f};
        z = __builtin_amdgcn_mfma_f32_16x16x32_bf16(ak0, bq0, z, 0, 0, 0);
        st[nt] = __builtin_amdgcn_mfma_f32_16x16x32_bf16(ak1, bq1, z, 0, 0, 0);
      }

      if (kt * 64 + 63 > qb * 128 + w * 16) {
#pragma unroll
        for (int nt = 0; nt < 4; ++nt)
#pragma unroll
          for (int i = 0; i < 4; ++i)
            if (kt * 64 + nt * 16 + quad * 4 + i > q_g) st[nt][i] = -1e30f;
      }

      float pm = -INFINITY;
#pragma unroll
      for (int nt = 0; nt < 4; ++nt)
#pragma unroll
        for (int i = 0; i < 4; ++i) pm = fmaxf(pm, st[nt][i]);
      pm = fmaxf(pm, __shfl_xor(pm, 16, 64));
      pm = fmaxf(pm, __shfl_xor(pm, 32, 64));
      float mn = fmaxf(m, pm);
      float alpha = __expf((m - mn) * 0.125f);
      m = mn;
      float p[4][4];
      float r = 0.f;
#pragma unroll
      for (int nt = 0; nt < 4; ++nt)
#pragma unroll
        for (int i = 0; i < 4; ++i) {
          p[nt][i] = __expf((st[nt][i] - mn) * 0.125f);
          r += p[nt][i];
        }
      r += __shfl_xor(r, 16, 64);
      r += __shfl_xor(r, 32, 64);
      l = l * alpha + r;
#pragma unroll
      for (int dt = 0; dt < 4; ++dt)
#pragma unroll
        for (int i = 0; i < 4; ++i) O[dt][i] *= alpha;

#pragma unroll
      for (int nt = 0; nt < 4; ++nt) {
        uint2 o = { pk_bf16(p[nt][0], p[nt][1]), pk_bf16(p[nt][2], p[nt][3]) };
        *(uint2*)&Ps[w][l15 * 72 + nt * 16 + quad * 4] = o;
      }
      s8v bp0 = *(const s8v*)&Ps[w][l15 * 72 + quad * 8];
      s8v bp1 = *(const s8v*)&Ps[w][l15 * 72 + 32 + quad * 8];
#pragma unroll
      for (int dt = 0; dt < 4; ++dt) {
        const short* p2 = &VTs[(dt * 16 + l15) * 72 + quad * 8];
        s8v av0 = *(const s8v*)p2;
        s8v av1 = *(const s8v*)(p2 + 32);
        O[dt] = __builtin_amdgcn_mfma_f32_16x16x32_bf16(av0, bp0, O[dt], 0, 0, 0);
        O[dt] = __builtin_amdgcn_mfma_f32_16x16x32_bf16(av1, bp1, O[dt], 0, 0, 0);
      }
    }

    __syncthreads();
    if (kt < ktmax) {
      *(uint4*)&Ks[prow * 72 + pd8] = pk;
      *(uint4*)&VTs[prow * 72 + pd8] = pv;
    }
    __syncthreads();
  }

  const float inv = 1.f / l;
  const size_t row = qrow0 + w * 16 + l15;
#pragma unroll
  for (int dt = 0; dt < 4; ++dt) {
    uint2 o = { pk_bf16(O[dt][0] * inv, O[dt][1] * inv),
                pk_bf16(O[dt][2] * inv, O[dt][3] * inv) };
    *(uint2*)&AOb[row * kD + dh + dt * 16 + quad * 4] = o;
  }
}

// ---------------------------------------------------------------------------
// WO-GEMM: out[t][d] = sum_e AO[t][e] * wob[d][e].  All-bf16, BK=64,
// global_load_lds swizzled staging for both operands.
// ---------------------------------------------------------------------------
__global__ __launch_bounds__(256) void wo_gemm(const u16* __restrict__ AOb,
                                               const u16* __restrict__ wob,
                                               float* __restrict__ out) {
  __shared__ short As[128 * 64];
  __shared__ short Bs[128 * 64];
  const int tid = threadIdx.x;
  const int lane = tid & 63, wid = tid >> 6;
  const int wm = wid & 1, wn = wid >> 1;
  const int quad = lane >> 4, l15 = lane & 15;
  const int dT = blockIdx.x * 128;
  const int tok0 = blockIdx.y * 128;

  f32x4 acc[4][4];
#pragma unroll
  for (int mt = 0; mt < 4; ++mt)
#pragma unroll
    for (int nt = 0; nt < 4; ++nt) acc[mt][nt] = {0.f, 0.f, 0.f, 0.f};

#pragma unroll 1
  for (int e0 = 0; e0 < kD; e0 += 64) {
    __syncthreads();
#pragma unroll
    for (int e = 0; e < 4; ++e) {                 // A: AO, DMA swizzled
      int flat = tid + e * 256;
      int r = flat >> 3, u = (flat & 7) ^ (r & 7);
      gl_lds16(&AOb[(size_t)(tok0 + r) * kD + e0 + u * 8], &As[flat * 8]);
    }
#pragma unroll
    for (int e = 0; e < 4; ++e) {                 // B: wob, DMA swizzled
      int flat = tid + e * 256;
      int r = flat >> 3, u = (flat & 7) ^ (r & 7);
      gl_lds16(&wob[(size_t)(dT + r) * kD + e0 + u * 8], &Bs[flat * 8]);
    }
    __syncthreads();
    s8v a0[4], a1[4], b0[4], b1[4];
#pragma unroll
    for (int mt = 0; mt < 4; ++mt) {
      int r = wm * 64 + mt * 16 + l15;
      a0[mt] = *(const s8v*)&As[r * 64 + ((quad) ^ (r & 7)) * 8];
      a1[mt] = *(const s8v*)&As[r * 64 + ((4 + quad) ^ (r & 7)) * 8];
    }
#pragma unroll
    for (int nt = 0; nt < 4; ++nt) {
      int r = wn * 64 + nt * 16 + l15;
      b0[nt] = *(const s8v*)&Bs[r * 64 + ((quad) ^ (r & 7)) * 8];
      b1[nt] = *(const s8v*)&Bs[r * 64 + ((4 + quad) ^ (r & 7)) * 8];
    }
#pragma unroll
    for (int mt = 0; mt < 4; ++mt)
#pragma unroll
      for (int nt = 0; nt < 4; ++nt) {
        acc[mt][nt] = __builtin_amdgcn_mfma_f32_16x16x32_bf16(
            a0[mt], b0[nt], acc[mt][nt], 0, 0, 0);
        acc[mt][nt] = __builtin_amdgcn_mfma_f32_16x16x32_bf16(
            a1[mt], b1[nt], acc[mt][nt], 0, 0, 0);
      }
  }
#pragma unroll
  for (int mt = 0; mt < 4; ++mt)
#pragma unroll
    for (int nt = 0; nt < 4; ++nt) {
      int col = dT + wn * 64 + nt * 16 + l15;
      int rbase = tok0 + wm * 64 + mt * 16 + quad * 4;
#pragma unroll
      for (int i = 0; i < 4; ++i)
        out[(size_t)(rbase + i) * kD + col] = acc[mt][nt][i];
    }
}

// ---------------------------------------------------------------------------
extern "C" void kernel_launch(void* const* d_in, const int* in_sizes, int n_in,
                              void* d_out, int out_size, void* d_ws, size_t ws_size,
                              hipStream_t stream) {
  const float* x     = (const float*)d_in[0];
  const float* fqk_w = (const float*)d_in[1];
  const float* fv_w  = (const float*)d_in[2];
  const float* wq    = (const float*)d_in[3];
  const float* wk    = (const float*)d_in[4];
  const float* wv    = (const float*)d_in[5];
  const float* f_neu = (const float*)d_in[6];
  const float* r_neu = (const float*)d_in[7];
  const float* WO    = (const float*)d_in[8];
  float* out = (float*)d_out;

  // ws layout (100 MB, lifetime-overlapped):
  //  [0,8)    FT (dead after g_gemm)
  //  [8,16)   RT (dead after v_gemm) -> wob [8,10) (conv_wo after v_gemm)
  //  [16,80)  G  (dead after reduce_h) -> Qb [16,32), Kb [32,48), VTg [48,64),
  //                                       AOb [64,80)
  //  [80,84)  h_qk, h_v
  //  [84,100) xb (bf16 x)
  char* ws = (char*)d_ws;
  u16*   FT   = (u16*)  (ws);
  u16*   RT   = (u16*)  (ws + ((size_t)8u  << 20));
  u16*   wob  = (u16*)  (ws + ((size_t)8u  << 20));
  u16*   G    = (u16*)  (ws + ((size_t)16u << 20));
  float* h_qk = (float*)(ws + ((size_t)80u << 20));
  float* h_v  = (float*)(ws + ((size_t)82u << 20));
  u16*   Qb   = (u16*)  (ws + ((size_t)16u << 20));
  u16*   Kb   = (u16*)  (ws + ((size_t)32u << 20));
  u16*   VTg  = (u16*)  (ws + ((size_t)48u << 20));
  u16*   AOb  = (u16*)  (ws + ((size_t)64u << 20));
  u16*   xb   = (u16*)  (ws + ((size_t)84u << 20));

  hipLaunchKernelGGL(conv_x, dim3(4096), dim3(256), 0, stream, x, xb);
  hipLaunchKernelGGL(t1_kernel, dim3(8, 64), dim3(256), 0, stream, f_neu, FT);
  hipLaunchKernelGGL(t2_kernel, dim3(8, 64), dim3(256), 0, stream, r_neu, RT);
  hipLaunchKernelGGL(g_gemm, dim3(32, 64), dim3(256), 0, stream, xb, FT, G);
  hipLaunchKernelGGL(reduce_h, dim3(512), dim3(256), 0, stream,
                     G, fqk_w, fv_w, h_qk, h_v);
  hipLaunchKernelGGL(qk_gemm, dim3(8, 64), dim3(512), 0, stream,
                     h_qk, wq, wk, RT, Qb, Kb);
  hipLaunchKernelGGL(v_gemm, dim3(8, 64), dim3(256), 0, stream,
                     h_v, wv, RT, VTg);
  hipLaunchKernelGGL(conv_wo, dim3(512), dim3(256), 0, stream, WO, wob);
  hipLaunchKernelGGL(attn_mfma, dim3(16, 16, 4), dim3(512), 0, stream,
                     Qb, Kb, VTg, AOb);
  hipLaunchKernelGGL(wo_gemm, dim3(8, 64), dim3(256), 0, stream,
                     AOb, wob, out);
}

// Round 10
// 482.088 us; speedup vs baseline: 1.0204x; 1.0204x over previous
//
#include <hip/hip_runtime.h>
#include <hip/hip_bf16.h>

// AttentionCircuit round 18 (= round 14 base + attn single-barrier dbuf):
//  - round 17's Q/K fusion reverted (qk 120us + v serialized = +27us total).
//    qkv_gemm frozen at round-14 form (~140us, 5 structural attempts all
//    regressed - local optimum for A-on-the-fly).
//  - attn_mfma: Ks/VTs double-buffered ([2][64*72]); prefetch regs (pk/pv)
//    write into buf^1 -> write target disjoint from read buffer -> ONE
//    __syncthreads per kt instead of two (the single barrier orders both
//    kt-writes->kt+1-reads and kt-reads->kt+1-writes). LDS 36864->55296
//    (2 blocks/CU) - measured occupancy-insensitive (r8 vs r11: 146 vs 144).
//  - attn qb work-balance swizzle, Qs-less Q loads, round-8 softmax kept.

namespace {
constexpr int kS = 2048;
constexpr int kD = 1024;
}

typedef unsigned short u16;
typedef __attribute__((ext_vector_type(2))) float f32x2;
typedef __attribute__((ext_vector_type(4))) float f32x4;
typedef __attribute__((ext_vector_type(8))) short s8v;   // 8 bf16 = 4 VGPRs

union FragU { s8v s; unsigned u[4]; };
union F4U { f32x4 v; f32x2 p[2]; };

__device__ __forceinline__ u16 f2bf_bits(float f) {
  union { float f; unsigned u; } cv; cv.f = f;
  unsigned u = cv.u;
  unsigned r = u + 0x7fffu + ((u >> 16) & 1u);   // RNE
  return (u16)(r >> 16);
}
__device__ __forceinline__ float bf2f(u16 b) {
  union { unsigned u; float f; } cv; cv.u = ((unsigned)b) << 16; return cv.f;
}
__device__ __forceinline__ unsigned pk_bf16(float a, float b) {
  __hip_bfloat162 h = __float22bfloat162_rn(make_float2(a, b));
  union { __hip_bfloat162 h; unsigned u; } cv; cv.h = h; return cv.u;
}
// async global->LDS, 16B per lane; LDS dest = wave-uniform base + lane*16
__device__ __forceinline__ void gl_lds16(const void* g, void* l) {
  __builtin_amdgcn_global_load_lds(
      (const __attribute__((address_space(1))) unsigned int*)g,
      (__attribute__((address_space(3))) unsigned int*)l, 16, 0, 0);
}

// ---------------------------------------------------------------------------
// conv_x: x fp32 -> xb bf16 (8 elems/thread).  conv_wo: same for W_O.
// ---------------------------------------------------------------------------
__global__ __launch_bounds__(256) void conv_x(const float* __restrict__ x,
                                              u16* __restrict__ xb) {
  int idx = blockIdx.x * 256 + threadIdx.x;
  float4 v0 = ((const float4*)x)[idx * 2];
  float4 v1 = ((const float4*)x)[idx * 2 + 1];
  uint4 o = { pk_bf16(v0.x, v0.y), pk_bf16(v0.z, v0.w),
              pk_bf16(v1.x, v1.y), pk_bf16(v1.z, v1.w) };
  ((uint4*)xb)[idx] = o;
}

// ---------------------------------------------------------------------------
// T1: FT[n*64+r][d] = f[n][d][r]  (bf16)  — B^T layout for G-GEMM.
// ---------------------------------------------------------------------------
__global__ __launch_bounds__(256) void t1_kernel(const float* __restrict__ f,
                                                 u16* __restrict__ FT) {
  __shared__ float Tt[64 * 132];
  const int tid = threadIdx.x;
  const int d0 = blockIdx.x * 128;
  const int n  = blockIdx.y;
#pragma unroll
  for (int e = 0; e < 8; ++e) {
    int flat = tid + e * 256;            // 0..2047
    int dd = flat >> 4, r4 = (flat & 15) * 4;
    float4 v = *(const float4*)&f[((size_t)n * kD + d0 + dd) * 64 + r4];
    Tt[(r4 + 0) * 132 + dd] = v.x;
    Tt[(r4 + 1) * 132 + dd] = v.y;
    Tt[(r4 + 2) * 132 + dd] = v.z;
    Tt[(r4 + 3) * 132 + dd] = v.w;
  }
  __syncthreads();
#pragma unroll
  for (int e = 0; e < 4; ++e) {
    int flat = tid + e * 256;            // 0..1023
    int r = flat >> 4, dq = (flat & 15) * 8;
    const float* p = &Tt[r * 132 + dq];
    uint4 o = { pk_bf16(p[0], p[1]), pk_bf16(p[2], p[3]),
                pk_bf16(p[4], p[5]), pk_bf16(p[6], p[7]) };
    *(uint4*)&FT[((size_t)n * 64 + r) * kD + d0 + dq] = o;
  }
}

// ---------------------------------------------------------------------------
// T2: RT[d][n*64+r] = r_neurons[n][r][d] (bf16) — B^T layout for QKV GEMM.
// ---------------------------------------------------------------------------
__global__ __launch_bounds__(256) void t2_kernel(const float* __restrict__ rn,
                                                 u16* __restrict__ RT) {
  __shared__ float Tt[128 * 68];
  const int tid = threadIdx.x;
  const int d0 = blockIdx.x * 128;
  const int n  = blockIdx.y;             // 0..63
#pragma unroll
  for (int e = 0; e < 8; ++e) {
    int flat = tid + e * 256;            // 0..2047
    int r = flat >> 5, d4 = (flat & 31) * 4;
    float4 v = *(const float4*)&rn[((size_t)n * 64 + r) * kD + d0 + d4];
    Tt[(d4 + 0) * 68 + r] = v.x;
    Tt[(d4 + 1) * 68 + r] = v.y;
    Tt[(d4 + 2) * 68 + r] = v.z;
    Tt[(d4 + 3) * 68 + r] = v.w;
  }
  __syncthreads();
#pragma unroll
  for (int e = 0; e < 4; ++e) {
    int flat = tid + e * 256;            // 0..1023
    int dd = flat >> 3, rq = (flat & 7) * 8;
    const float* p = &Tt[dd * 68 + rq];
    uint4 o = { pk_bf16(p[0], p[1]), pk_bf16(p[2], p[3]),
                pk_bf16(p[4], p[5]), pk_bf16(p[6], p[7]) };
    *(uint4*)&RT[((size_t)(d0 + dd)) * 4096 + n * 64 + rq] = o;
  }
}

// ---------------------------------------------------------------------------
// G-GEMM: G[t][g] = sum_d xb[t,d] * FT[g][d].  128x128 tile, BK=64.
// Unpadded swizzled LDS (row r unit u at u^(r&7)), global_load_lds staging.
// ---------------------------------------------------------------------------
__global__ __launch_bounds__(256) void g_gemm(const u16* __restrict__ xb,
                                              const u16* __restrict__ FT,
                                              u16* __restrict__ G) {
  __shared__ short As[128 * 64];
  __shared__ short Bs[128 * 64];
  const int tid = threadIdx.x;
  const int lane = tid & 63, wid = tid >> 6;
  const int wm = wid & 1, wn = wid >> 1;
  const int quad = lane >> 4, l15 = lane & 15;
  const int cT = blockIdx.x * 128;
  const int tok0 = blockIdx.y * 128;

  f32x4 acc[4][4];
#pragma unroll
  for (int mt = 0; mt < 4; ++mt)
#pragma unroll
    for (int nt = 0; nt < 4; ++nt) acc[mt][nt] = {0.f, 0.f, 0.f, 0.f};

#pragma unroll 1
  for (int d0 = 0; d0 < kD; d0 += 64) {
    __syncthreads();
#pragma unroll
    for (int e = 0; e < 4; ++e) {                 // A: 128x64, DMA swizzled
      int flat = tid + e * 256;                   // 0..1023 (16B units)
      int r = flat >> 3, u = (flat & 7) ^ (r & 7);
      gl_lds16(&xb[(size_t)(tok0 + r) * kD + d0 + u * 8], &As[flat * 8]);
    }
#pragma unroll
    for (int e = 0; e < 4; ++e) {                 // B: 128x64, DMA swizzled
      int flat = tid + e * 256;
      int r = flat >> 3, u = (flat & 7) ^ (r & 7);
      gl_lds16(&FT[(size_t)(cT + r) * kD + d0 + u * 8], &Bs[flat * 8]);
    }
    __syncthreads();
    s8v a0[4], a1[4], b0[4], b1[4];
#pragma unroll
    for (int mt = 0; mt < 4; ++mt) {
      int r = wm * 64 + mt * 16 + l15;
      a0[mt] = *(const s8v*)&As[r * 64 + ((quad) ^ (r & 7)) * 8];
      a1[mt] = *(const s8v*)&As[r * 64 + ((4 + quad) ^ (r & 7)) * 8];
    }
#pragma unroll
    for (int nt = 0; nt < 4; ++nt) {
      int r = wn * 64 + nt * 16 + l15;
      b0[nt] = *(const s8v*)&Bs[r * 64 + ((quad) ^ (r & 7)) * 8];
      b1[nt] = *(const s8v*)&Bs[r * 64 + ((4 + quad) ^ (r & 7)) * 8];
    }
#pragma unroll
    for (int mt = 0; mt < 4; ++mt)
#pragma unroll
      for (int nt = 0; nt < 4; ++nt) {
        acc[mt][nt] = __builtin_amdgcn_mfma_f32_16x16x32_bf16(
            a0[mt], b0[nt], acc[mt][nt], 0, 0, 0);
        acc[mt][nt] = __builtin_amdgcn_mfma_f32_16x16x32_bf16(
            a1[mt], b1[nt], acc[mt][nt], 0, 0, 0);
      }
  }
#pragma unroll
  for (int mt = 0; mt < 4; ++mt)
#pragma unroll
    for (int nt = 0; nt < 4; ++nt) {
      int col = cT + wn * 64 + nt * 16 + l15;
      int rbase = tok0 + wm * 64 + mt * 16 + quad * 4;
#pragma unroll
      for (int i = 0; i < 4; ++i)
        G[(size_t)(rbase + i) * 4096 + col] = f2bf_bits(acc[mt][nt][i]);
    }
}

// ---------------------------------------------------------------------------
// reduce_h: h_qk[t][r] = sum_n fqk_w[t][n]*G[t][n*64+r]; h_v from cols 2048+.
// ---------------------------------------------------------------------------
__global__ __launch_bounds__(256) void reduce_h(const u16* __restrict__ G,
                                                const float* __restrict__ fqk_w,
                                                const float* __restrict__ fv_w,
                                                float* __restrict__ h_qk,
                                                float* __restrict__ h_v) {
  int idx = blockIdx.x * 256 + threadIdx.x;    // 0..131071
  int t = idx >> 4, r4 = (idx & 15) * 4;
  float4 aq = {0.f, 0.f, 0.f, 0.f}, av = {0.f, 0.f, 0.f, 0.f};
  const u16* gq = &G[(size_t)t * 4096 + r4];
  const u16* gv = gq + 2048;
#pragma unroll 4
  for (int n = 0; n < 32; ++n) {
    float wa = fqk_w[t * 32 + n];
    float wb = fv_w[t * 32 + n];
    ushort4 g1 = *(const ushort4*)&gq[n * 64];
    ushort4 g2 = *(const ushort4*)&gv[n * 64];
    aq.x += wa * bf2f(g1.x); aq.y += wa * bf2f(g1.y);
    aq.z += wa * bf2f(g1.z); aq.w += wa * bf2f(g1.w);
    av.x += wb * bf2f(g2.x); av.y += wb * bf2f(g2.y);
    av.z += wb * bf2f(g2.z); av.w += wb * bf2f(g2.w);
  }
  *(float4*)&h_qk[t * 64 + r4] = aq;
  *(float4*)&h_v[t * 64 + r4] = av;
}

// ---------------------------------------------------------------------------
// QKV-GEMM: C[t][d] = sum_g (w[t,n]*h[t,r]) * RT[d][g0+g],  g=n*64+r, K=2048.
// Round-12 structure (BK=64). Packing multiplies as f32x2 (round 14).
// which: 0->Qb (bf16, [t][d]), 1->Kb (bf16, [t][d]), 2->VTg ([b][h][d][s]).
// ---------------------------------------------------------------------------
__global__ __launch_bounds__(256) void qkv_gemm(
    const float* __restrict__ h_qk, const float* __restrict__ h_v,
    const float* __restrict__ wq, const float* __restrict__ wk,
    const float* __restrict__ wv, const u16* __restrict__ RT,
    u16* __restrict__ Qb, u16* __restrict__ Kb, u16* __restrict__ VTg) {
  __shared__ float hs[128 * 68];                 // aliased by Bs after hoist
  __shared__ float wsl[128 * 33];
  short* Bs = (short*)hs;                        // needs 128*64*2 = 16 KB
  const int tid = threadIdx.x;
  const int lane = tid & 63, wid = tid >> 6;
  const int wm = wid & 1, wn = wid >> 1;
  const int quad = lane >> 4, l15 = lane & 15;
  const int dT = blockIdx.x * 128;
  const int tok0 = blockIdx.y * 128;
  const int which = blockIdx.z;
  const float* __restrict__ h = (which == 2) ? h_v : h_qk;
  const float* __restrict__ w = (which == 0) ? wq : (which == 1) ? wk : wv;
  const int g0 = (which == 2) ? 2048 : 0;

#pragma unroll
  for (int e = 0; e < 8; ++e) {                  // h tile: 128x64 fp32
    int flat = tid + e * 256;                    // 0..2047 (float4 units)
    int row = flat >> 4, rq = (flat & 15) * 4;
    *(float4*)&hs[row * 68 + rq] =
        *(const float4*)&h[(size_t)(tok0 + row) * 64 + rq];
  }
#pragma unroll
  for (int e = 0; e < 16; ++e) {                 // w tile: 128x32 fp32
    int flat = tid + e * 256;                    // 0..4095
    int row = flat >> 5, nn = flat & 31;
    wsl[row * 33 + nn] = w[(size_t)(tok0 + row) * 32 + nn];
  }
  __syncthreads();

  f32x4 hreg[4][4];
#pragma unroll
  for (int mt = 0; mt < 4; ++mt) {
    const float* hp = &hs[(wm * 64 + mt * 16 + l15) * 68 + quad * 8];
    hreg[mt][0] = *(const f32x4*)hp;
    hreg[mt][1] = *(const f32x4*)(hp + 4);
    hreg[mt][2] = *(const f32x4*)(hp + 32);
    hreg[mt][3] = *(const f32x4*)(hp + 36);
  }

  f32x4 acc[4][4];
#pragma unroll
  for (int mt = 0; mt < 4; ++mt)
#pragma unroll
    for (int nt = 0; nt < 4; ++nt) acc[mt][nt] = {0.f, 0.f, 0.f, 0.f};

#pragma unroll 1
  for (int n = 0; n < 32; ++n) {
    __syncthreads();                             // hs reads done / prev iter
#pragma unroll
    for (int e = 0; e < 4; ++e) {                // B: 128x64, DMA swizzled
      int flat = tid + e * 256;                  // 0..1023 (16B units)
      int r = flat >> 3, u = (flat & 7) ^ (r & 7);
      gl_lds16(&RT[(size_t)(dT + r) * 4096 + g0 + n * 64 + u * 8],
               &Bs[flat * 8]);
    }
    __syncthreads();
    s8v a0[4], a1[4], b0[4], b1[4];
#pragma unroll
    for (int mt = 0; mt < 4; ++mt) {
      float wv_ = wsl[(wm * 64 + mt * 16 + l15) * 33 + n];
      f32x2 w2 = {wv_, wv_};
      F4U h0, h1, h2, h3;
      h0.v = hreg[mt][0]; h1.v = hreg[mt][1];
      h2.v = hreg[mt][2]; h3.v = hreg[mt][3];
      f32x2 a00 = w2 * h0.p[0], a01 = w2 * h0.p[1];
      f32x2 a10 = w2 * h1.p[0], a11 = w2 * h1.p[1];
      f32x2 a20 = w2 * h2.p[0], a21 = w2 * h2.p[1];
      f32x2 a30 = w2 * h3.p[0], a31 = w2 * h3.p[1];
      FragU fa, fb;
      fa.u[0] = pk_bf16(a00[0], a00[1]);
      fa.u[1] = pk_bf16(a01[0], a01[1]);
      fa.u[2] = pk_bf16(a10[0], a10[1]);
      fa.u[3] = pk_bf16(a11[0], a11[1]);
      a0[mt] = fa.s;
      fb.u[0] = pk_bf16(a20[0], a20[1]);
      fb.u[1] = pk_bf16(a21[0], a21[1]);
      fb.u[2] = pk_bf16(a30[0], a30[1]);
      fb.u[3] = pk_bf16(a31[0], a31[1]);
      a1[mt] = fb.s;
    }
#pragma unroll
    for (int nt = 0; nt < 4; ++nt) {
      int r = wn * 64 + nt * 16 + l15;
      b0[nt] = *(const s8v*)&Bs[r * 64 + ((quad) ^ (r & 7)) * 8];
      b1[nt] = *(const s8v*)&Bs[r * 64 + ((4 + quad) ^ (r & 7)) * 8];
    }
#pragma unroll
    for (int mt = 0; mt < 4; ++mt)
#pragma unroll
      for (int nt = 0; nt < 4; ++nt) {
        acc[mt][nt] = __builtin_amdgcn_mfma_f32_16x16x32_bf16(
            a0[mt], b0[nt], acc[mt][nt], 0, 0, 0);
        acc[mt][nt] = __builtin_amdgcn_mfma_f32_16x16x32_bf16(
            a1[mt], b1[nt], acc[mt][nt], 0, 0, 0);
      }
  }

  if (which < 2) {
    u16* __restrict__ O = (which == 0) ? Qb : Kb;
#pragma unroll
    for (int mt = 0; mt < 4; ++mt)
#pragma unroll
      for (int nt = 0; nt < 4; ++nt) {
        int col = dT + wn * 64 + nt * 16 + l15;
        int rbase = tok0 + wm * 64 + mt * 16 + quad * 4;
#pragma unroll
        for (int i = 0; i < 4; ++i)
          O[(size_t)(rbase + i) * kD + col] = f2bf_bits(acc[mt][nt][i]);
      }
  } else {
#pragma unroll
    for (int mt = 0; mt < 4; ++mt)
#pragma unroll
      for (int nt = 0; nt < 4; ++nt) {
        int d = dT + wn * 64 + nt * 16 + l15;
        int hh = d >> 6, dl = d & 63;
        int t = tok0 + wm * 64 + mt * 16 + quad * 4;   // 4 consecutive tokens
        int bb = t >> 11, sl = t & 2047;
        ushort4 u = { f2bf_bits(acc[mt][nt][0]), f2bf_bits(acc[mt][nt][1]),
                      f2bf_bits(acc[mt][nt][2]), f2bf_bits(acc[mt][nt][3]) };
        *(ushort4*)&VTg[(((size_t)bb * 16 + hh) * 64 + dl) * kS + sl] = u;
      }
  }
}

// ---------------------------------------------------------------------------
// conv_wo: W_O fp32 -> bf16 (runs after qkv_gemm, into dead RT region).
// ---------------------------------------------------------------------------
__global__ __launch_bounds__(256) void conv_wo(const float* __restrict__ WO,
                                               u16* __restrict__ wob) {
  int idx = blockIdx.x * 256 + threadIdx.x;
  float4 v0 = ((const float4*)WO)[idx * 2];
  float4 v1 = ((const float4*)WO)[idx * 2 + 1];
  uint4 o = { pk_bf16(v0.x, v0.y), pk_bf16(v0.z, v0.w),
              pk_bf16(v1.x, v1.y), pk_bf16(v1.z, v1.w) };
  ((uint4*)wob)[idx] = o;
}

// ---------------------------------------------------------------------------
// Flash attention, transposed-score MFMA.
// Round 18: Ks/VTs double-buffered -> ONE __syncthreads per kt (was 2).
// Race-safe: iter kt reads buf[kt&1], writes prefetch into buf[~kt&1]
// (disjoint); the single end-of-iter barrier orders kt-writes vs kt+1-reads
// AND kt-reads vs kt+1-writes. qb swizzle + Qs-less Q + round-8 softmax.
// ---------------------------------------------------------------------------
__global__ __launch_bounds__(512) void attn_mfma(
    const u16* __restrict__ Qb, const u16* __restrict__ Kb,
    const u16* __restrict__ VTg, u16* __restrict__ AOb)
{
  __shared__ short Ks[2][64 * 72];    // [buf][k-tok][d]
  __shared__ short VTs[2][64 * 72];   // [buf][d][k-tok]
  __shared__ short Ps[8][16 * 72];    // per-wave P strip [q-local][k-tok]
  const int tid = threadIdx.x;
  const int lane = tid & 63, w = tid >> 6;       // w 0..7
  const int quad = lane >> 4, l15 = lane & 15;
  const int qb = (blockIdx.x + blockIdx.y + 4 * blockIdx.z) & 15;
  const int hh = blockIdx.y, b = blockIdx.z;
  const int dh = hh * 64;
  const size_t qrow0 = (size_t)b * kS + (size_t)qb * 128;
  const int ktmax = qb * 2 + 1;
  const u16* __restrict__ vbase = VTg + ((size_t)(b * 16 + hh) * 64) * kS;

  const int prow = tid >> 3;                     // 0..63
  const int pd8  = (tid & 7) * 8;                // 16B staging mapping

  *(uint4*)&Ks[0][prow * 72 + pd8] =
      *(const uint4*)&Kb[((size_t)b * kS + prow) * kD + dh + pd8];
  *(uint4*)&VTs[0][prow * 72 + pd8] =
      *(const uint4*)&vbase[(size_t)prow * kS + pd8];

  // Q fragments: one-time per-wave direct global load
  const size_t qrow = qrow0 + w * 16 + l15;
  s8v bq0 = *(const s8v*)&Qb[qrow * kD + dh + quad * 8];
  s8v bq1 = *(const s8v*)&Qb[qrow * kD + dh + 32 + quad * 8];
  __syncthreads();

  const int q_g = qb * 128 + w * 16 + l15;
  const int qmax_w = qb * 128 + w * 16 + 15;
  float m = -INFINITY, l = 0.f;
  f32x4 O[4];
#pragma unroll
  for (int dt = 0; dt < 4; ++dt) O[dt] = {0.f, 0.f, 0.f, 0.f};

#pragma unroll 1
  for (int kt = 0; kt <= ktmax; ++kt) {
    const int cur = kt & 1, nxt = cur ^ 1;
    uint4 pk, pv;
    if (kt < ktmax) {
      const size_t krn = (size_t)b * kS + (size_t)(kt + 1) * 64;
      pk = *(const uint4*)&Kb[(krn + prow) * kD + dh + pd8];
      pv = *(const uint4*)&vbase[(size_t)prow * kS + (kt + 1) * 64 + pd8];
    }

    if (kt * 64 <= qmax_w) {
      f32x4 st[4];
#pragma unroll
      for (int nt = 0; nt < 4; ++nt) {
        const short* p = &Ks[cur][(nt * 16 + l15) * 72 + quad * 8];
        s8v ak0 = *(const s8v*)p;
        s8v ak1 = *(const s8v*)(p + 32);
        f32x4 z = {0.f, 0.f, 0.f, 0.f};
        z = __builtin_amdgcn_mfma_f32_16x16x32_bf16(ak0, bq0, z, 0, 0, 0);
        st[nt] = __builtin_amdgcn_mfma_f32_16x16x32_bf16(ak1, bq1, z, 0, 0, 0);
      }

      if (kt * 64 + 63 > qb * 128 + w * 16) {
#pragma unroll
        for (int nt = 0; nt < 4; ++nt)
#pragma unroll
          for (int i = 0; i < 4; ++i)
            if (kt * 64 + nt * 16 + quad * 4 + i > q_g) st[nt][i] = -1e30f;
      }

      float pm = -INFINITY;
#pragma unroll
      for (int nt = 0; nt < 4; ++nt)
#pragma unroll
        for (int i = 0; i < 4; ++i) pm = fmaxf(pm, st[nt][i]);
      pm = fmaxf(pm, __shfl_xor(pm, 16, 64));
      pm = fmaxf(pm, __shfl_xor(pm, 32, 64));
      float mn = fmaxf(m, pm);
      float alpha = __expf((m - mn) * 0.125f);
      m = mn;
      float p[4][4];
      float r = 0.f;
#pragma unroll
      for (int nt = 0; nt < 4; ++nt)
#pragma unroll
        for (int i = 0; i < 4; ++i) {
          p[nt][i] = __expf((st[nt][i] - mn) * 0.125f);
          r += p[nt][i];
        }
      r += __shfl_xor(r, 16, 64);
      r += __shfl_xor(r, 32, 64);
      l = l * alpha + r;
#pragma unroll
      for (int dt = 0; dt < 4; ++dt)
#pragma unroll
        for (int i = 0; i < 4; ++i) O[dt][i] *= alpha;

#pragma unroll
      for (int nt = 0; nt < 4; ++nt) {
        uint2 o = { pk_bf16(p[nt][0], p[nt][1]), pk_bf16(p[nt][2], p[nt][3]) };
        *(uint2*)&Ps[w][l15 * 72 + nt * 16 + quad * 4] = o;
      }
      s8v bp0 = *(const s8v*)&Ps[w][l15 * 72 + quad * 8];
      s8v bp1 = *(const s8v*)&Ps[w][l15 * 72 + 32 + quad * 8];
#pragma unroll
      for (int dt = 0; dt < 4; ++dt) {
        const short* p2 = &VTs[cur][(dt * 16 + l15) * 72 + quad * 8];
        s8v av0 = *(const s8v*)p2;
        s8v av1 = *(const s8v*)(p2 + 32);
        O[dt] = __builtin_amdgcn_mfma_f32_16x16x32_bf16(av0, bp0, O[dt], 0, 0, 0);
        O[dt] = __builtin_amdgcn_mfma_f32_16x16x32_bf16(av1, bp1, O[dt], 0, 0, 0);
      }
    }

    if (kt < ktmax) {                            // write into the OTHER buf
      *(uint4*)&Ks[nxt][prow * 72 + pd8] = pk;
      *(uint4*)&VTs[nxt][prow * 72 + pd8] = pv;
    }
    __syncthreads();                             // single barrier per iter
  }

  const float inv = 1.f / l;
  const size_t row = qrow0 + w * 16 + l15;
#pragma unroll
  for (int dt = 0; dt < 4; ++dt) {
    uint2 o = { pk_bf16(O[dt][0] * inv, O[dt][1] * inv),
                pk_bf16(O[dt][2] * inv, O[dt][3] * inv) };
    *(uint2*)&AOb[row * kD + dh + dt * 16 + quad * 4] = o;
  }
}

// ---------------------------------------------------------------------------
// WO-GEMM: out[t][d] = sum_e AO[t][e] * wob[d][e].  All-bf16, BK=64,
// global_load_lds swizzled staging for both operands.
// ---------------------------------------------------------------------------
__global__ __launch_bounds__(256) void wo_gemm(const u16* __restrict__ AOb,
                                               const u16* __restrict__ wob,
                                               float* __restrict__ out) {
  __shared__ short As[128 * 64];
  __shared__ short Bs[128 * 64];
  const int tid = threadIdx.x;
  const int lane = tid & 63, wid = tid >> 6;
  const int wm = wid & 1, wn = wid >> 1;
  const int quad = lane >> 4, l15 = lane & 15;
  const int dT = blockIdx.x * 128;
  const int tok0 = blockIdx.y * 128;

  f32x4 acc[4][4];
#pragma unroll
  for (int mt = 0; mt < 4; ++mt)
#pragma unroll
    for (int nt = 0; nt < 4; ++nt) acc[mt][nt] = {0.f, 0.f, 0.f, 0.f};

#pragma unroll 1
  for (int e0 = 0; e0 < kD; e0 += 64) {
    __syncthreads();
#pragma unroll
    for (int e = 0; e < 4; ++e) {                 // A: AO, DMA swizzled
      int flat = tid + e * 256;
      int r = flat >> 3, u = (flat & 7) ^ (r & 7);
      gl_lds16(&AOb[(size_t)(tok0 + r) * kD + e0 + u * 8], &As[flat * 8]);
    }
#pragma unroll
    for (int e = 0; e < 4; ++e) {                 // B: wob, DMA swizzled
      int flat = tid + e * 256;
      int r = flat >> 3, u = (flat & 7) ^ (r & 7);
      gl_lds16(&wob[(size_t)(dT + r) * kD + e0 + u * 8], &Bs[flat * 8]);
    }
    __syncthreads();
    s8v a0[4], a1[4], b0[4], b1[4];
#pragma unroll
    for (int mt = 0; mt < 4; ++mt) {
      int r = wm * 64 + mt * 16 + l15;
      a0[mt] = *(const s8v*)&As[r * 64 + ((quad) ^ (r & 7)) * 8];
      a1[mt] = *(const s8v*)&As[r * 64 + ((4 + quad) ^ (r & 7)) * 8];
    }
#pragma unroll
    for (int nt = 0; nt < 4; ++nt) {
      int r = wn * 64 + nt * 16 + l15;
      b0[nt] = *(const s8v*)&Bs[r * 64 + ((quad) ^ (r & 7)) * 8];
      b1[nt] = *(const s8v*)&Bs[r * 64 + ((4 + quad) ^ (r & 7)) * 8];
    }
#pragma unroll
    for (int mt = 0; mt < 4; ++mt)
#pragma unroll
      for (int nt = 0; nt < 4; ++nt) {
        acc[mt][nt] = __builtin_amdgcn_mfma_f32_16x16x32_bf16(
            a0[mt], b0[nt], acc[mt][nt], 0, 0, 0);
        acc[mt][nt] = __builtin_amdgcn_mfma_f32_16x16x32_bf16(
            a1[mt], b1[nt], acc[mt][nt], 0, 0, 0);
      }
  }
#pragma unroll
  for (int mt = 0; mt < 4; ++mt)
#pragma unroll
    for (int nt = 0; nt < 4; ++nt) {
      int col = dT + wn * 64 + nt * 16 + l15;
      int rbase = tok0 + wm * 64 + mt * 16 + quad * 4;
#pragma unroll
      for (int i = 0; i < 4; ++i)
        out[(size_t)(rbase + i) * kD + col] = acc[mt][nt][i];
    }
}

// ---------------------------------------------------------------------------
extern "C" void kernel_launch(void* const* d_in, const int* in_sizes, int n_in,
                              void* d_out, int out_size, void* d_ws, size_t ws_size,
                              hipStream_t stream) {
  const float* x     = (const float*)d_in[0];
  const float* fqk_w = (const float*)d_in[1];
  const float* fv_w  = (const float*)d_in[2];
  const float* wq    = (const float*)d_in[3];
  const float* wk    = (const float*)d_in[4];
  const float* wv    = (const float*)d_in[5];
  const float* f_neu = (const float*)d_in[6];
  const float* r_neu = (const float*)d_in[7];
  const float* WO    = (const float*)d_in[8];
  float* out = (float*)d_out;

  // ws layout (100 MB, lifetime-overlapped):
  //  [0,8)    FT (dead after g_gemm)
  //  [8,16)   RT (dead after qkv_gemm) -> wob [8,10) (conv_wo after qkv)
  //  [16,80)  G  (dead after reduce_h) -> Qb [16,32), Kb [32,48), VTg [48,64),
  //                                       AOb [64,80)
  //  [80,84)  h_qk, h_v
  //  [84,100) xb (bf16 x)
  char* ws = (char*)d_ws;
  u16*   FT   = (u16*)  (ws);
  u16*   RT   = (u16*)  (ws + ((size_t)8u  << 20));
  u16*   wob  = (u16*)  (ws + ((size_t)8u  << 20));
  u16*   G    = (u16*)  (ws + ((size_t)16u << 20));
  float* h_qk = (float*)(ws + ((size_t)80u << 20));
  float* h_v  = (float*)(ws + ((size_t)82u << 20));
  u16*   Qb   = (u16*)  (ws + ((size_t)16u << 20));
  u16*   Kb   = (u16*)  (ws + ((size_t)32u << 20));
  u16*   VTg  = (u16*)  (ws + ((size_t)48u << 20));
  u16*   AOb  = (u16*)  (ws + ((size_t)64u << 20));
  u16*   xb   = (u16*)  (ws + ((size_t)84u << 20));

  hipLaunchKernelGGL(conv_x, dim3(4096), dim3(256), 0, stream, x, xb);
  hipLaunchKernelGGL(t1_kernel, dim3(8, 64), dim3(256), 0, stream, f_neu, FT);
  hipLaunchKernelGGL(t2_kernel, dim3(8, 64), dim3(256), 0, stream, r_neu, RT);
  hipLaunchKernelGGL(g_gemm, dim3(32, 64), dim3(256), 0, stream, xb, FT, G);
  hipLaunchKernelGGL(reduce_h, dim3(512), dim3(256), 0, stream,
                     G, fqk_w, fv_w, h_qk, h_v);
  hipLaunchKernelGGL(qkv_gemm, dim3(8, 64, 3), dim3(256), 0, stream,
                     h_qk, h_v, wq, wk, wv, RT, Qb, Kb, VTg);
  hipLaunchKernelGGL(conv_wo, dim3(512), dim3(256), 0, stream, WO, wob);
  hipLaunchKernelGGL(attn_mfma, dim3(16, 16, 4), dim3(512), 0, stream,
                     Qb, Kb, VTg, AOb);
  hipLaunchKernelGGL(wo_gemm, dim3(8, 64), dim3(256), 0, stream,
                     AOb, wob, out);
}

// Round 11
// 452.967 us; speedup vs baseline: 1.0860x; 1.0643x over previous
//
#include <hip/hip_runtime.h>
#include <hip/hip_bf16.h>

// AttentionCircuit round 19 (= round 14 base + qkv wave-retile 32x128):
//  - attn r18 dbuf reverted (occupancy loss beat barrier saving; 482 vs 464).
//    attn = round-12 form (qb swizzle, Qs-less, round-8 softmax, 2 barriers).
//  - qkv_gemm: wave tiling 64x64 (mt=4,nt=4) -> 32x128 (mt=2,nt=8).
//    A-pack VALU per n-step halves (96->48 ops; VALUBusy 52% was the
//    co-bottleneck vs MfmaUtil 32%); cost is +8 ds_read_b128/iter on the
//    lightly-loaded LDS pipe. Same math, same verified staging/barriers.
//    hreg 64->32 VGPR, a-frags 32->16, b-frags 32->64; acc in AGPRs.

namespace {
constexpr int kS = 2048;
constexpr int kD = 1024;
}

typedef unsigned short u16;
typedef __attribute__((ext_vector_type(2))) float f32x2;
typedef __attribute__((ext_vector_type(4))) float f32x4;
typedef __attribute__((ext_vector_type(8))) short s8v;   // 8 bf16 = 4 VGPRs

union FragU { s8v s; unsigned u[4]; };
union F4U { f32x4 v; f32x2 p[2]; };

__device__ __forceinline__ u16 f2bf_bits(float f) {
  union { float f; unsigned u; } cv; cv.f = f;
  unsigned u = cv.u;
  unsigned r = u + 0x7fffu + ((u >> 16) & 1u);   // RNE
  return (u16)(r >> 16);
}
__device__ __forceinline__ float bf2f(u16 b) {
  union { unsigned u; float f; } cv; cv.u = ((unsigned)b) << 16; return cv.f;
}
__device__ __forceinline__ unsigned pk_bf16(float a, float b) {
  __hip_bfloat162 h = __float22bfloat162_rn(make_float2(a, b));
  union { __hip_bfloat162 h; unsigned u; } cv; cv.h = h; return cv.u;
}
// async global->LDS, 16B per lane; LDS dest = wave-uniform base + lane*16
__device__ __forceinline__ void gl_lds16(const void* g, void* l) {
  __builtin_amdgcn_global_load_lds(
      (const __attribute__((address_space(1))) unsigned int*)g,
      (__attribute__((address_space(3))) unsigned int*)l, 16, 0, 0);
}

// ---------------------------------------------------------------------------
// conv_x: x fp32 -> xb bf16 (8 elems/thread).  conv_wo: same for W_O.
// ---------------------------------------------------------------------------
__global__ __launch_bounds__(256) void conv_x(const float* __restrict__ x,
                                              u16* __restrict__ xb) {
  int idx = blockIdx.x * 256 + threadIdx.x;
  float4 v0 = ((const float4*)x)[idx * 2];
  float4 v1 = ((const float4*)x)[idx * 2 + 1];
  uint4 o = { pk_bf16(v0.x, v0.y), pk_bf16(v0.z, v0.w),
              pk_bf16(v1.x, v1.y), pk_bf16(v1.z, v1.w) };
  ((uint4*)xb)[idx] = o;
}

// ---------------------------------------------------------------------------
// T1: FT[n*64+r][d] = f[n][d][r]  (bf16)  — B^T layout for G-GEMM.
// ---------------------------------------------------------------------------
__global__ __launch_bounds__(256) void t1_kernel(const float* __restrict__ f,
                                                 u16* __restrict__ FT) {
  __shared__ float Tt[64 * 132];
  const int tid = threadIdx.x;
  const int d0 = blockIdx.x * 128;
  const int n  = blockIdx.y;
#pragma unroll
  for (int e = 0; e < 8; ++e) {
    int flat = tid + e * 256;            // 0..2047
    int dd = flat >> 4, r4 = (flat & 15) * 4;
    float4 v = *(const float4*)&f[((size_t)n * kD + d0 + dd) * 64 + r4];
    Tt[(r4 + 0) * 132 + dd] = v.x;
    Tt[(r4 + 1) * 132 + dd] = v.y;
    Tt[(r4 + 2) * 132 + dd] = v.z;
    Tt[(r4 + 3) * 132 + dd] = v.w;
  }
  __syncthreads();
#pragma unroll
  for (int e = 0; e < 4; ++e) {
    int flat = tid + e * 256;            // 0..1023
    int r = flat >> 4, dq = (flat & 15) * 8;
    const float* p = &Tt[r * 132 + dq];
    uint4 o = { pk_bf16(p[0], p[1]), pk_bf16(p[2], p[3]),
                pk_bf16(p[4], p[5]), pk_bf16(p[6], p[7]) };
    *(uint4*)&FT[((size_t)n * 64 + r) * kD + d0 + dq] = o;
  }
}

// ---------------------------------------------------------------------------
// T2: RT[d][n*64+r] = r_neurons[n][r][d] (bf16) — B^T layout for QKV GEMM.
// ---------------------------------------------------------------------------
__global__ __launch_bounds__(256) void t2_kernel(const float* __restrict__ rn,
                                                 u16* __restrict__ RT) {
  __shared__ float Tt[128 * 68];
  const int tid = threadIdx.x;
  const int d0 = blockIdx.x * 128;
  const int n  = blockIdx.y;             // 0..63
#pragma unroll
  for (int e = 0; e < 8; ++e) {
    int flat = tid + e * 256;            // 0..2047
    int r = flat >> 5, d4 = (flat & 31) * 4;
    float4 v = *(const float4*)&rn[((size_t)n * 64 + r) * kD + d0 + d4];
    Tt[(d4 + 0) * 68 + r] = v.x;
    Tt[(d4 + 1) * 68 + r] = v.y;
    Tt[(d4 + 2) * 68 + r] = v.z;
    Tt[(d4 + 3) * 68 + r] = v.w;
  }
  __syncthreads();
#pragma unroll
  for (int e = 0; e < 4; ++e) {
    int flat = tid + e * 256;            // 0..1023
    int dd = flat >> 3, rq = (flat & 7) * 8;
    const float* p = &Tt[dd * 68 + rq];
    uint4 o = { pk_bf16(p[0], p[1]), pk_bf16(p[2], p[3]),
                pk_bf16(p[4], p[5]), pk_bf16(p[6], p[7]) };
    *(uint4*)&RT[((size_t)(d0 + dd)) * 4096 + n * 64 + rq] = o;
  }
}

// ---------------------------------------------------------------------------
// G-GEMM: G[t][g] = sum_d xb[t,d] * FT[g][d].  128x128 tile, BK=64.
// Unpadded swizzled LDS (row r unit u at u^(r&7)), global_load_lds staging.
// ---------------------------------------------------------------------------
__global__ __launch_bounds__(256) void g_gemm(const u16* __restrict__ xb,
                                              const u16* __restrict__ FT,
                                              u16* __restrict__ G) {
  __shared__ short As[128 * 64];
  __shared__ short Bs[128 * 64];
  const int tid = threadIdx.x;
  const int lane = tid & 63, wid = tid >> 6;
  const int wm = wid & 1, wn = wid >> 1;
  const int quad = lane >> 4, l15 = lane & 15;
  const int cT = blockIdx.x * 128;
  const int tok0 = blockIdx.y * 128;

  f32x4 acc[4][4];
#pragma unroll
  for (int mt = 0; mt < 4; ++mt)
#pragma unroll
    for (int nt = 0; nt < 4; ++nt) acc[mt][nt] = {0.f, 0.f, 0.f, 0.f};

#pragma unroll 1
  for (int d0 = 0; d0 < kD; d0 += 64) {
    __syncthreads();
#pragma unroll
    for (int e = 0; e < 4; ++e) {                 // A: 128x64, DMA swizzled
      int flat = tid + e * 256;                   // 0..1023 (16B units)
      int r = flat >> 3, u = (flat & 7) ^ (r & 7);
      gl_lds16(&xb[(size_t)(tok0 + r) * kD + d0 + u * 8], &As[flat * 8]);
    }
#pragma unroll
    for (int e = 0; e < 4; ++e) {                 // B: 128x64, DMA swizzled
      int flat = tid + e * 256;
      int r = flat >> 3, u = (flat & 7) ^ (r & 7);
      gl_lds16(&FT[(size_t)(cT + r) * kD + d0 + u * 8], &Bs[flat * 8]);
    }
    __syncthreads();
    s8v a0[4], a1[4], b0[4], b1[4];
#pragma unroll
    for (int mt = 0; mt < 4; ++mt) {
      int r = wm * 64 + mt * 16 + l15;
      a0[mt] = *(const s8v*)&As[r * 64 + ((quad) ^ (r & 7)) * 8];
      a1[mt] = *(const s8v*)&As[r * 64 + ((4 + quad) ^ (r & 7)) * 8];
    }
#pragma unroll
    for (int nt = 0; nt < 4; ++nt) {
      int r = wn * 64 + nt * 16 + l15;
      b0[nt] = *(const s8v*)&Bs[r * 64 + ((quad) ^ (r & 7)) * 8];
      b1[nt] = *(const s8v*)&Bs[r * 64 + ((4 + quad) ^ (r & 7)) * 8];
    }
#pragma unroll
    for (int mt = 0; mt < 4; ++mt)
#pragma unroll
      for (int nt = 0; nt < 4; ++nt) {
        acc[mt][nt] = __builtin_amdgcn_mfma_f32_16x16x32_bf16(
            a0[mt], b0[nt], acc[mt][nt], 0, 0, 0);
        acc[mt][nt] = __builtin_amdgcn_mfma_f32_16x16x32_bf16(
            a1[mt], b1[nt], acc[mt][nt], 0, 0, 0);
      }
  }
#pragma unroll
  for (int mt = 0; mt < 4; ++mt)
#pragma unroll
    for (int nt = 0; nt < 4; ++nt) {
      int col = cT + wn * 64 + nt * 16 + l15;
      int rbase = tok0 + wm * 64 + mt * 16 + quad * 4;
#pragma unroll
      for (int i = 0; i < 4; ++i)
        G[(size_t)(rbase + i) * 4096 + col] = f2bf_bits(acc[mt][nt][i]);
    }
}

// ---------------------------------------------------------------------------
// reduce_h: h_qk[t][r] = sum_n fqk_w[t][n]*G[t][n*64+r]; h_v from cols 2048+.
// ---------------------------------------------------------------------------
__global__ __launch_bounds__(256) void reduce_h(const u16* __restrict__ G,
                                                const float* __restrict__ fqk_w,
                                                const float* __restrict__ fv_w,
                                                float* __restrict__ h_qk,
                                                float* __restrict__ h_v) {
  int idx = blockIdx.x * 256 + threadIdx.x;    // 0..131071
  int t = idx >> 4, r4 = (idx & 15) * 4;
  float4 aq = {0.f, 0.f, 0.f, 0.f}, av = {0.f, 0.f, 0.f, 0.f};
  const u16* gq = &G[(size_t)t * 4096 + r4];
  const u16* gv = gq + 2048;
#pragma unroll 4
  for (int n = 0; n < 32; ++n) {
    float wa = fqk_w[t * 32 + n];
    float wb = fv_w[t * 32 + n];
    ushort4 g1 = *(const ushort4*)&gq[n * 64];
    ushort4 g2 = *(const ushort4*)&gv[n * 64];
    aq.x += wa * bf2f(g1.x); aq.y += wa * bf2f(g1.y);
    aq.z += wa * bf2f(g1.z); aq.w += wa * bf2f(g1.w);
    av.x += wb * bf2f(g2.x); av.y += wb * bf2f(g2.y);
    av.z += wb * bf2f(g2.z); av.w += wb * bf2f(g2.w);
  }
  *(float4*)&h_qk[t * 64 + r4] = aq;
  *(float4*)&h_v[t * 64 + r4] = av;
}

// ---------------------------------------------------------------------------
// QKV-GEMM: C[t][d] = sum_g (w[t,n]*h[t,r]) * RT[d][g0+g],  g=n*64+r, K=2048.
// Round 19: wave tiling 32x128 (mt=2, nt=8) - halves A-pack VALU per n-step
// (the 52%-busy co-bottleneck pipe), +8 ds_read_b128 on the light LDS pipe.
// Same BK=64 staging / swizzle / 2-barrier loop as round 12 (verified).
// which: 0->Qb (bf16, [t][d]), 1->Kb (bf16, [t][d]), 2->VTg ([b][h][d][s]).
// ---------------------------------------------------------------------------
__global__ __launch_bounds__(256) void qkv_gemm(
    const float* __restrict__ h_qk, const float* __restrict__ h_v,
    const float* __restrict__ wq, const float* __restrict__ wk,
    const float* __restrict__ wv, const u16* __restrict__ RT,
    u16* __restrict__ Qb, u16* __restrict__ Kb, u16* __restrict__ VTg) {
  __shared__ float hs[128 * 68];                 // aliased by Bs after hoist
  __shared__ float wsl[128 * 33];
  short* Bs = (short*)hs;                        // needs 128*64*2 = 16 KB
  const int tid = threadIdx.x;
  const int lane = tid & 63, wid = tid >> 6;     // wid 0..3 = M-strip of 32
  const int quad = lane >> 4, l15 = lane & 15;
  const int dT = blockIdx.x * 128;
  const int tok0 = blockIdx.y * 128;
  const int which = blockIdx.z;
  const float* __restrict__ h = (which == 2) ? h_v : h_qk;
  const float* __restrict__ w = (which == 0) ? wq : (which == 1) ? wk : wv;
  const int g0 = (which == 2) ? 2048 : 0;

#pragma unroll
  for (int e = 0; e < 8; ++e) {                  // h tile: 128x64 fp32
    int flat = tid + e * 256;                    // 0..2047 (float4 units)
    int row = flat >> 4, rq = (flat & 15) * 4;
    *(float4*)&hs[row * 68 + rq] =
        *(const float4*)&h[(size_t)(tok0 + row) * 64 + rq];
  }
#pragma unroll
  for (int e = 0; e < 16; ++e) {                 // w tile: 128x32 fp32
    int flat = tid + e * 256;                    // 0..4095
    int row = flat >> 5, nn = flat & 31;
    wsl[row * 33 + nn] = w[(size_t)(tok0 + row) * 32 + nn];
  }
  __syncthreads();

  f32x4 hreg[2][4];
#pragma unroll
  for (int mt = 0; mt < 2; ++mt) {
    const float* hp = &hs[(wid * 32 + mt * 16 + l15) * 68 + quad * 8];
    hreg[mt][0] = *(const f32x4*)hp;
    hreg[mt][1] = *(const f32x4*)(hp + 4);
    hreg[mt][2] = *(const f32x4*)(hp + 32);
    hreg[mt][3] = *(const f32x4*)(hp + 36);
  }

  f32x4 acc[2][8];
#pragma unroll
  for (int mt = 0; mt < 2; ++mt)
#pragma unroll
    for (int nt = 0; nt < 8; ++nt) acc[mt][nt] = {0.f, 0.f, 0.f, 0.f};

#pragma unroll 1
  for (int n = 0; n < 32; ++n) {
    __syncthreads();                             // hs reads done / prev iter
#pragma unroll
    for (int e = 0; e < 4; ++e) {                // B: 128x64, DMA swizzled
      int flat = tid + e * 256;                  // 0..1023 (16B units)
      int r = flat >> 3, u = (flat & 7) ^ (r & 7);
      gl_lds16(&RT[(size_t)(dT + r) * 4096 + g0 + n * 64 + u * 8],
               &Bs[flat * 8]);
    }
    __syncthreads();
    s8v a0[2], a1[2], b0[8], b1[8];
#pragma unroll
    for (int mt = 0; mt < 2; ++mt) {
      float wv_ = wsl[(wid * 32 + mt * 16 + l15) * 33 + n];
      f32x2 w2 = {wv_, wv_};
      F4U h0, h1, h2, h3;
      h0.v = hreg[mt][0]; h1.v = hreg[mt][1];
      h2.v = hreg[mt][2]; h3.v = hreg[mt][3];
      f32x2 a00 = w2 * h0.p[0], a01 = w2 * h0.p[1];
      f32x2 a10 = w2 * h1.p[0], a11 = w2 * h1.p[1];
      f32x2 a20 = w2 * h2.p[0], a21 = w2 * h2.p[1];
      f32x2 a30 = w2 * h3.p[0], a31 = w2 * h3.p[1];
      FragU fa, fb;
      fa.u[0] = pk_bf16(a00[0], a00[1]);
      fa.u[1] = pk_bf16(a01[0], a01[1]);
      fa.u[2] = pk_bf16(a10[0], a10[1]);
      fa.u[3] = pk_bf16(a11[0], a11[1]);
      a0[mt] = fa.s;
      fb.u[0] = pk_bf16(a20[0], a20[1]);
      fb.u[1] = pk_bf16(a21[0], a21[1]);
      fb.u[2] = pk_bf16(a30[0], a30[1]);
      fb.u[3] = pk_bf16(a31[0], a31[1]);
      a1[mt] = fb.s;
    }
#pragma unroll
    for (int nt = 0; nt < 8; ++nt) {
      int r = nt * 16 + l15;
      b0[nt] = *(const s8v*)&Bs[r * 64 + ((quad) ^ (r & 7)) * 8];
      b1[nt] = *(const s8v*)&Bs[r * 64 + ((4 + quad) ^ (r & 7)) * 8];
    }
#pragma unroll
    for (int mt = 0; mt < 2; ++mt)
#pragma unroll
      for (int nt = 0; nt < 8; ++nt) {
        acc[mt][nt] = __builtin_amdgcn_mfma_f32_16x16x32_bf16(
            a0[mt], b0[nt], acc[mt][nt], 0, 0, 0);
        acc[mt][nt] = __builtin_amdgcn_mfma_f32_16x16x32_bf16(
            a1[mt], b1[nt], acc[mt][nt], 0, 0, 0);
      }
  }

  if (which < 2) {
    u16* __restrict__ O = (which == 0) ? Qb : Kb;
#pragma unroll
    for (int mt = 0; mt < 2; ++mt)
#pragma unroll
      for (int nt = 0; nt < 8; ++nt) {
        int col = dT + nt * 16 + l15;
        int rbase = tok0 + wid * 32 + mt * 16 + quad * 4;
#pragma unroll
        for (int i = 0; i < 4; ++i)
          O[(size_t)(rbase + i) * kD + col] = f2bf_bits(acc[mt][nt][i]);
      }
  } else {
#pragma unroll
    for (int mt = 0; mt < 2; ++mt)
#pragma unroll
      for (int nt = 0; nt < 8; ++nt) {
        int d = dT + nt * 16 + l15;
        int hh = d >> 6, dl = d & 63;
        int t = tok0 + wid * 32 + mt * 16 + quad * 4;  // 4 consecutive tokens
        int bb = t >> 11, sl = t & 2047;
        ushort4 u = { f2bf_bits(acc[mt][nt][0]), f2bf_bits(acc[mt][nt][1]),
                      f2bf_bits(acc[mt][nt][2]), f2bf_bits(acc[mt][nt][3]) };
        *(ushort4*)&VTg[(((size_t)bb * 16 + hh) * 64 + dl) * kS + sl] = u;
      }
  }
}

// ---------------------------------------------------------------------------
// conv_wo: W_O fp32 -> bf16 (runs after qkv_gemm, into dead RT region).
// ---------------------------------------------------------------------------
__global__ __launch_bounds__(256) void conv_wo(const float* __restrict__ WO,
                                               u16* __restrict__ wob) {
  int idx = blockIdx.x * 256 + threadIdx.x;
  float4 v0 = ((const float4*)WO)[idx * 2];
  float4 v1 = ((const float4*)WO)[idx * 2 + 1];
  uint4 o = { pk_bf16(v0.x, v0.y), pk_bf16(v0.z, v0.w),
              pk_bf16(v1.x, v1.y), pk_bf16(v1.z, v1.w) };
  ((uint4*)wob)[idx] = o;
}

// ---------------------------------------------------------------------------
// Flash attention, transposed-score MFMA.
// Round 12 config (best measured): qb swizzle, no Qs LDS tile, round-8
// softmax, single-buffered Ks/VTs with 2 barriers (r18 dbuf reverted).
// ---------------------------------------------------------------------------
__global__ __launch_bounds__(512) void attn_mfma(
    const u16* __restrict__ Qb, const u16* __restrict__ Kb,
    const u16* __restrict__ VTg, u16* __restrict__ AOb)
{
  __shared__ short Ks[64 * 72];       // [k-tok][d]
  __shared__ short VTs[64 * 72];      // [d][k-tok]
  __shared__ short Ps[8][16 * 72];    // per-wave P strip [q-local][k-tok]
  const int tid = threadIdx.x;
  const int lane = tid & 63, w = tid >> 6;       // w 0..7
  const int quad = lane >> 4, l15 = lane & 15;
  const int qb = (blockIdx.x + blockIdx.y + 4 * blockIdx.z) & 15;
  const int hh = blockIdx.y, b = blockIdx.z;
  const int dh = hh * 64;
  const size_t qrow0 = (size_t)b * kS + (size_t)qb * 128;
  const int ktmax = qb * 2 + 1;
  const u16* __restrict__ vbase = VTg + ((size_t)(b * 16 + hh) * 64) * kS;

  const int prow = tid >> 3;                     // 0..63
  const int pd8  = (tid & 7) * 8;                // 16B staging mapping

  *(uint4*)&Ks[prow * 72 + pd8] =
      *(const uint4*)&Kb[((size_t)b * kS + prow) * kD + dh + pd8];
  *(uint4*)&VTs[prow * 72 + pd8] =
      *(const uint4*)&vbase[(size_t)prow * kS + pd8];

  // Q fragments: one-time per-wave direct global load
  const size_t qrow = qrow0 + w * 16 + l15;
  s8v bq0 = *(const s8v*)&Qb[qrow * kD + dh + quad * 8];
  s8v bq1 = *(const s8v*)&Qb[qrow * kD + dh + 32 + quad * 8];
  __syncthreads();

  const int q_g = qb * 128 + w * 16 + l15;
  const int qmax_w = qb * 128 + w * 16 + 15;
  float m = -INFINITY, l = 0.f;
  f32x4 O[4];
#pragma unroll
  for (int dt = 0; dt < 4; ++dt) O[dt] = {0.f, 0.f, 0.f, 0.f};

#pragma unroll 1
  for (int kt = 0; kt <= ktmax; ++kt) {
    uint4 pk, pv;
    if (kt < ktmax) {
      const size_t krn = (size_t)b * kS + (size_t)(kt + 1) * 64;
      pk = *(const uint4*)&Kb[(krn + prow) * kD + dh + pd8];
      pv = *(const uint4*)&vbase[(size_t)prow * kS + (kt + 1) * 64 + pd8];
    }

    if (kt * 64 <= qmax_w) {
      f32x4 st[4];
#pragma unroll
      for (int nt = 0; nt < 4; ++nt) {
        const short* p = &Ks[(nt * 16 + l15) * 72 + quad * 8];
        s8v ak0 = *(const s8v*)p;
        s8v ak1 = *(const s8v*)(p + 32);
        f32x4 z = {0.f, 0.f, 0.f, 0.f};
        z = __builtin_amdgcn_mfma_f32_16x16x32_bf16(ak0, bq0, z, 0, 0, 0);
        st[nt] = __builtin_amdgcn_mfma_f32_16x16x32_bf16(ak1, bq1, z, 0, 0, 0);
      }

      if (kt * 64 + 63 > qb * 128 + w * 16) {
#pragma unroll
        for (int nt = 0; nt < 4; ++nt)
#pragma unroll
          for (int i = 0; i < 4; ++i)
            if (kt * 64 + nt * 16 + quad * 4 + i > q_g) st[nt][i] = -1e30f;
      }

      float pm = -INFINITY;
#pragma unroll
      for (int nt = 0; nt < 4; ++nt)
#pragma unroll
        for (int i = 0; i < 4; ++i) pm = fmaxf(pm, st[nt][i]);
      pm = fmaxf(pm, __shfl_xor(pm, 16, 64));
      pm = fmaxf(pm, __shfl_xor(pm, 32, 64));
      float mn = fmaxf(m, pm);
      float alpha = __expf((m - mn) * 0.125f);
      m = mn;
      float p[4][4];
      float r = 0.f;
#pragma unroll
      for (int nt = 0; nt < 4; ++nt)
#pragma unroll
        for (int i = 0; i < 4; ++i) {
          p[nt][i] = __expf((st[nt][i] - mn) * 0.125f);
          r += p[nt][i];
        }
      r += __shfl_xor(r, 16, 64);
      r += __shfl_xor(r, 32, 64);
      l = l * alpha + r;
#pragma unroll
      for (int dt = 0; dt < 4; ++dt)
#pragma unroll
        for (int i = 0; i < 4; ++i) O[dt][i] *= alpha;

#pragma unroll
      for (int nt = 0; nt < 4; ++nt) {
        uint2 o = { pk_bf16(p[nt][0], p[nt][1]), pk_bf16(p[nt][2], p[nt][3]) };
        *(uint2*)&Ps[w][l15 * 72 + nt * 16 + quad * 4] = o;
      }
      s8v bp0 = *(const s8v*)&Ps[w][l15 * 72 + quad * 8];
      s8v bp1 = *(const s8v*)&Ps[w][l15 * 72 + 32 + quad * 8];
#pragma unroll
      for (int dt = 0; dt < 4; ++dt) {
        const short* p2 = &VTs[(dt * 16 + l15) * 72 + quad * 8];
        s8v av0 = *(const s8v*)p2;
        s8v av1 = *(const s8v*)(p2 + 32);
        O[dt] = __builtin_amdgcn_mfma_f32_16x16x32_bf16(av0, bp0, O[dt], 0, 0, 0);
        O[dt] = __builtin_amdgcn_mfma_f32_16x16x32_bf16(av1, bp1, O[dt], 0, 0, 0);
      }
    }

    __syncthreads();
    if (kt < ktmax) {
      *(uint4*)&Ks[prow * 72 + pd8] = pk;
      *(uint4*)&VTs[prow * 72 + pd8] = pv;
    }
    __syncthreads();
  }

  const float inv = 1.f / l;
  const size_t row = qrow0 + w * 16 + l15;
#pragma unroll
  for (int dt = 0; dt < 4; ++dt) {
    uint2 o = { pk_bf16(O[dt][0] * inv, O[dt][1] * inv),
                pk_bf16(O[dt][2] * inv, O[dt][3] * inv) };
    *(uint2*)&AOb[row * kD + dh + dt * 16 + quad * 4] = o;
  }
}

// ---------------------------------------------------------------------------
// WO-GEMM: out[t][d] = sum_e AO[t][e] * wob[d][e].  All-bf16, BK=64,
// global_load_lds swizzled staging for both operands.
// ---------------------------------------------------------------------------
__global__ __launch_bounds__(256) void wo_gemm(const u16* __restrict__ AOb,
                                               const u16* __restrict__ wob,
                                               float* __restrict__ out) {
  __shared__ short As[128 * 64];
  __shared__ short Bs[128 * 64];
  const int tid = threadIdx.x;
  const int lane = tid & 63, wid = tid >> 6;
  const int wm = wid & 1, wn = wid >> 1;
  const int quad = lane >> 4, l15 = lane & 15;
  const int dT = blockIdx.x * 128;
  const int tok0 = blockIdx.y * 128;

  f32x4 acc[4][4];
#pragma unroll
  for (int mt = 0; mt < 4; ++mt)
#pragma unroll
    for (int nt = 0; nt < 4; ++nt) acc[mt][nt] = {0.f, 0.f, 0.f, 0.f};

#pragma unroll 1
  for (int e0 = 0; e0 < kD; e0 += 64) {
    __syncthreads();
#pragma unroll
    for (int e = 0; e < 4; ++e) {                 // A: AO, DMA swizzled
      int flat = tid + e * 256;
      int r = flat >> 3, u = (flat & 7) ^ (r & 7);
      gl_lds16(&AOb[(size_t)(tok0 + r) * kD + e0 + u * 8], &As[flat * 8]);
    }
#pragma unroll
    for (int e = 0; e < 4; ++e) {                 // B: wob, DMA swizzled
      int flat = tid + e * 256;
      int r = flat >> 3, u = (flat & 7) ^ (r & 7);
      gl_lds16(&wob[(size_t)(dT + r) * kD + e0 + u * 8], &Bs[flat * 8]);
    }
    __syncthreads();
    s8v a0[4], a1[4], b0[4], b1[4];
#pragma unroll
    for (int mt = 0; mt < 4; ++mt) {
      int r = wm * 64 + mt * 16 + l15;
      a0[mt] = *(const s8v*)&As[r * 64 + ((quad) ^ (r & 7)) * 8];
      a1[mt] = *(const s8v*)&As[r * 64 + ((4 + quad) ^ (r & 7)) * 8];
    }
#pragma unroll
    for (int nt = 0; nt < 4; ++nt) {
      int r = wn * 64 + nt * 16 + l15;
      b0[nt] = *(const s8v*)&Bs[r * 64 + ((quad) ^ (r & 7)) * 8];
      b1[nt] = *(const s8v*)&Bs[r * 64 + ((4 + quad) ^ (r & 7)) * 8];
    }
#pragma unroll
    for (int mt = 0; mt < 4; ++mt)
#pragma unroll
      for (int nt = 0; nt < 4; ++nt) {
        acc[mt][nt] = __builtin_amdgcn_mfma_f32_16x16x32_bf16(
            a0[mt], b0[nt], acc[mt][nt], 0, 0, 0);
        acc[mt][nt] = __builtin_amdgcn_mfma_f32_16x16x32_bf16(
            a1[mt], b1[nt], acc[mt][nt], 0, 0, 0);
      }
  }
#pragma unroll
  for (int mt = 0; mt < 4; ++mt)
#pragma unroll
    for (int nt = 0; nt < 4; ++nt) {
      int col = dT + wn * 64 + nt * 16 + l15;
      int rbase = tok0 + wm * 64 + mt * 16 + quad * 4;
#pragma unroll
      for (int i = 0; i < 4; ++i)
        out[(size_t)(rbase + i) * kD + col] = acc[mt][nt][i];
    }
}

// ---------------------------------------------------------------------------
extern "C" void kernel_launch(void* const* d_in, const int* in_sizes, int n_in,
                              void* d_out, int out_size, void* d_ws, size_t ws_size,
                              hipStream_t stream) {
  const float* x     = (const float*)d_in[0];
  const float* fqk_w = (const float*)d_in[1];
  const float* fv_w  = (const float*)d_in[2];
  const float* wq    = (const float*)d_in[3];
  const float* wk    = (const float*)d_in[4];
  const float* wv    = (const float*)d_in[5];
  const float* f_neu = (const float*)d_in[6];
  const float* r_neu = (const float*)d_in[7];
  const float* WO    = (const float*)d_in[8];
  float* out = (float*)d_out;

  // ws layout (100 MB, lifetime-overlapped):
  //  [0,8)    FT (dead after g_gemm)
  //  [8,16)   RT (dead after qkv_gemm) -> wob [8,10) (conv_wo after qkv)
  //  [16,80)  G  (dead after reduce_h) -> Qb [16,32), Kb [32,48), VTg [48,64),
  //                                       AOb [64,80)
  //  [80,84)  h_qk, h_v
  //  [84,100) xb (bf16 x)
  char* ws = (char*)d_ws;
  u16*   FT   = (u16*)  (ws);
  u16*   RT   = (u16*)  (ws + ((size_t)8u  << 20));
  u16*   wob  = (u16*)  (ws + ((size_t)8u  << 20));
  u16*   G    = (u16*)  (ws + ((size_t)16u << 20));
  float* h_qk = (float*)(ws + ((size_t)80u << 20));
  float* h_v  = (float*)(ws + ((size_t)82u << 20));
  u16*   Qb   = (u16*)  (ws + ((size_t)16u << 20));
  u16*   Kb   = (u16*)  (ws + ((size_t)32u << 20));
  u16*   VTg  = (u16*)  (ws + ((size_t)48u << 20));
  u16*   AOb  = (u16*)  (ws + ((size_t)64u << 20));
  u16*   xb   = (u16*)  (ws + ((size_t)84u << 20));

  hipLaunchKernelGGL(conv_x, dim3(4096), dim3(256), 0, stream, x, xb);
  hipLaunchKernelGGL(t1_kernel, dim3(8, 64), dim3(256), 0, stream, f_neu, FT);
  hipLaunchKernelGGL(t2_kernel, dim3(8, 64), dim3(256), 0, stream, r_neu, RT);
  hipLaunchKernelGGL(g_gemm, dim3(32, 64), dim3(256), 0, stream, xb, FT, G);
  hipLaunchKernelGGL(reduce_h, dim3(512), dim3(256), 0, stream,
                     G, fqk_w, fv_w, h_qk, h_v);
  hipLaunchKernelGGL(qkv_gemm, dim3(8, 64, 3), dim3(256), 0, stream,
                     h_qk, h_v, wq, wk, wv, RT, Qb, Kb, VTg);
  hipLaunchKernelGGL(conv_wo, dim3(512), dim3(256), 0, stream, WO, wob);
  hipLaunchKernelGGL(attn_mfma, dim3(16, 16, 4), dim3(512), 0, stream,
                     Qb, Kb, VTg, AOb);
  hipLaunchKernelGGL(wo_gemm, dim3(8, 64), dim3(256), 0, stream,
                     AOb, wob, out);
}

// Round 12
// 438.366 us; speedup vs baseline: 1.1221x; 1.0333x over previous
//
#include <hip/hip_runtime.h>
#include <hip/hip_bf16.h>

// AttentionCircuit round 20 (= round 19 + launch fusion + attn setprio):
//  - prep = conv_x + t1 + t2 fused (independent kernels, 1 launch, branch on
//    blockIdx.x; t1/t2 blocks first). Saves 2 launch gaps.
//  - reduce_h_wo = reduce_h + conv_wo fused; wob relocated to dead xb region
//    (ws+84MB; xb dead after g_gemm, reduce_h_wo runs after g_gemm). 1 gap.
//  - attn_mfma: s_setprio(1) around QK and PV MFMA clusters, ISOLATED this
//    time. r10's test was confounded and pre-dated the qb swizzle (lockstep
//    same-qb blocks = m190 hurt-regime); post-r12 each CU holds 4 different-
//    qb blocks = m191's +4-7% regime.
//  - qkv_gemm frozen at round-19 32x128 retile (125us, VALU/MFMA balanced).

namespace {
constexpr int kS = 2048;
constexpr int kD = 1024;
}

typedef unsigned short u16;
typedef __attribute__((ext_vector_type(2))) float f32x2;
typedef __attribute__((ext_vector_type(4))) float f32x4;
typedef __attribute__((ext_vector_type(8))) short s8v;   // 8 bf16 = 4 VGPRs

union FragU { s8v s; unsigned u[4]; };
union F4U { f32x4 v; f32x2 p[2]; };

__device__ __forceinline__ u16 f2bf_bits(float f) {
  union { float f; unsigned u; } cv; cv.f = f;
  unsigned u = cv.u;
  unsigned r = u + 0x7fffu + ((u >> 16) & 1u);   // RNE
  return (u16)(r >> 16);
}
__device__ __forceinline__ float bf2f(u16 b) {
  union { unsigned u; float f; } cv; cv.u = ((unsigned)b) << 16; return cv.f;
}
__device__ __forceinline__ unsigned pk_bf16(float a, float b) {
  __hip_bfloat162 h = __float22bfloat162_rn(make_float2(a, b));
  union { __hip_bfloat162 h; unsigned u; } cv; cv.h = h; return cv.u;
}
// async global->LDS, 16B per lane; LDS dest = wave-uniform base + lane*16
__device__ __forceinline__ void gl_lds16(const void* g, void* l) {
  __builtin_amdgcn_global_load_lds(
      (const __attribute__((address_space(1))) unsigned int*)g,
      (__attribute__((address_space(3))) unsigned int*)l, 16, 0, 0);
}

// ---------------------------------------------------------------------------
// prep: fused conv_x + t1 + t2 (all independent; one launch).
//  blocks [0,512)    : t1  — FT[n*64+r][d] = f[n][d][r] (bf16)
//  blocks [512,1024) : t2  — RT[d][n*64+r] = rn[n][r][d] (bf16)
//  blocks [1024,5120): conv_x — xb = bf16(x), 8 elems/thread
// ---------------------------------------------------------------------------
__global__ __launch_bounds__(256) void prep(
    const float* __restrict__ x, u16* __restrict__ xb,
    const float* __restrict__ f, u16* __restrict__ FT,
    const float* __restrict__ rn, u16* __restrict__ RT) {
  __shared__ float Tt[128 * 68];                 // t2 needs 34816 B (max)
  const int tid = threadIdx.x;
  const int bx = blockIdx.x;

  if (bx < 512) {                                // ---- t1 ----
    float* T1 = Tt;                              // uses 64*132 = 33792 B
    const int d0 = (bx & 7) * 128;
    const int n  = bx >> 3;
#pragma unroll
    for (int e = 0; e < 8; ++e) {
      int flat = tid + e * 256;                  // 0..2047
      int dd = flat >> 4, r4 = (flat & 15) * 4;
      float4 v = *(const float4*)&f[((size_t)n * kD + d0 + dd) * 64 + r4];
      T1[(r4 + 0) * 132 + dd] = v.x;
      T1[(r4 + 1) * 132 + dd] = v.y;
      T1[(r4 + 2) * 132 + dd] = v.z;
      T1[(r4 + 3) * 132 + dd] = v.w;
    }
    __syncthreads();
#pragma unroll
    for (int e = 0; e < 4; ++e) {
      int flat = tid + e * 256;                  // 0..1023
      int r = flat >> 4, dq = (flat & 15) * 8;
      const float* p = &T1[r * 132 + dq];
      uint4 o = { pk_bf16(p[0], p[1]), pk_bf16(p[2], p[3]),
                  pk_bf16(p[4], p[5]), pk_bf16(p[6], p[7]) };
      *(uint4*)&FT[((size_t)n * 64 + r) * kD + d0 + dq] = o;
    }
  } else if (bx < 1024) {                        // ---- t2 ----
    const int b2 = bx - 512;
    const int d0 = (b2 & 7) * 128;
    const int n  = b2 >> 3;
#pragma unroll
    for (int e = 0; e < 8; ++e) {
      int flat = tid + e * 256;                  // 0..2047
      int r = flat >> 5, d4 = (flat & 31) * 4;
      float4 v = *(const float4*)&rn[((size_t)n * 64 + r) * kD + d0 + d4];
      Tt[(d4 + 0) * 68 + r] = v.x;
      Tt[(d4 + 1) * 68 + r] = v.y;
      Tt[(d4 + 2) * 68 + r] = v.z;
      Tt[(d4 + 3) * 68 + r] = v.w;
    }
    __syncthreads();
#pragma unroll
    for (int e = 0; e < 4; ++e) {
      int flat = tid + e * 256;                  // 0..1023
      int dd = flat >> 3, rq = (flat & 7) * 8;
      const float* p = &Tt[dd * 68 + rq];
      uint4 o = { pk_bf16(p[0], p[1]), pk_bf16(p[2], p[3]),
                  pk_bf16(p[4], p[5]), pk_bf16(p[6], p[7]) };
      *(uint4*)&RT[((size_t)(d0 + dd)) * 4096 + n * 64 + rq] = o;
    }
  } else {                                       // ---- conv_x ----
    int idx = (bx - 1024) * 256 + tid;
    float4 v0 = ((const float4*)x)[idx * 2];
    float4 v1 = ((const float4*)x)[idx * 2 + 1];
    uint4 o = { pk_bf16(v0.x, v0.y), pk_bf16(v0.z, v0.w),
                pk_bf16(v1.x, v1.y), pk_bf16(v1.z, v1.w) };
    ((uint4*)xb)[idx] = o;
  }
}

// ---------------------------------------------------------------------------
// G-GEMM: G[t][g] = sum_d xb[t,d] * FT[g][d].  128x128 tile, BK=64.
// Unpadded swizzled LDS (row r unit u at u^(r&7)), global_load_lds staging.
// ---------------------------------------------------------------------------
__global__ __launch_bounds__(256) void g_gemm(const u16* __restrict__ xb,
                                              const u16* __restrict__ FT,
                                              u16* __restrict__ G) {
  __shared__ short As[128 * 64];
  __shared__ short Bs[128 * 64];
  const int tid = threadIdx.x;
  const int lane = tid & 63, wid = tid >> 6;
  const int wm = wid & 1, wn = wid >> 1;
  const int quad = lane >> 4, l15 = lane & 15;
  const int cT = blockIdx.x * 128;
  const int tok0 = blockIdx.y * 128;

  f32x4 acc[4][4];
#pragma unroll
  for (int mt = 0; mt < 4; ++mt)
#pragma unroll
    for (int nt = 0; nt < 4; ++nt) acc[mt][nt] = {0.f, 0.f, 0.f, 0.f};

#pragma unroll 1
  for (int d0 = 0; d0 < kD; d0 += 64) {
    __syncthreads();
#pragma unroll
    for (int e = 0; e < 4; ++e) {                 // A: 128x64, DMA swizzled
      int flat = tid + e * 256;                   // 0..1023 (16B units)
      int r = flat >> 3, u = (flat & 7) ^ (r & 7);
      gl_lds16(&xb[(size_t)(tok0 + r) * kD + d0 + u * 8], &As[flat * 8]);
    }
#pragma unroll
    for (int e = 0; e < 4; ++e) {                 // B: 128x64, DMA swizzled
      int flat = tid + e * 256;
      int r = flat >> 3, u = (flat & 7) ^ (r & 7);
      gl_lds16(&FT[(size_t)(cT + r) * kD + d0 + u * 8], &Bs[flat * 8]);
    }
    __syncthreads();
    s8v a0[4], a1[4], b0[4], b1[4];
#pragma unroll
    for (int mt = 0; mt < 4; ++mt) {
      int r = wm * 64 + mt * 16 + l15;
      a0[mt] = *(const s8v*)&As[r * 64 + ((quad) ^ (r & 7)) * 8];
      a1[mt] = *(const s8v*)&As[r * 64 + ((4 + quad) ^ (r & 7)) * 8];
    }
#pragma unroll
    for (int nt = 0; nt < 4; ++nt) {
      int r = wn * 64 + nt * 16 + l15;
      b0[nt] = *(const s8v*)&Bs[r * 64 + ((quad) ^ (r & 7)) * 8];
      b1[nt] = *(const s8v*)&Bs[r * 64 + ((4 + quad) ^ (r & 7)) * 8];
    }
#pragma unroll
    for (int mt = 0; mt < 4; ++mt)
#pragma unroll
      for (int nt = 0; nt < 4; ++nt) {
        acc[mt][nt] = __builtin_amdgcn_mfma_f32_16x16x32_bf16(
            a0[mt], b0[nt], acc[mt][nt], 0, 0, 0);
        acc[mt][nt] = __builtin_amdgcn_mfma_f32_16x16x32_bf16(
            a1[mt], b1[nt], acc[mt][nt], 0, 0, 0);
      }
  }
#pragma unroll
  for (int mt = 0; mt < 4; ++mt)
#pragma unroll
    for (int nt = 0; nt < 4; ++nt) {
      int col = cT + wn * 64 + nt * 16 + l15;
      int rbase = tok0 + wm * 64 + mt * 16 + quad * 4;
#pragma unroll
      for (int i = 0; i < 4; ++i)
        G[(size_t)(rbase + i) * 4096 + col] = f2bf_bits(acc[mt][nt][i]);
    }
}

// ---------------------------------------------------------------------------
// reduce_h_wo: fused reduce_h + conv_wo (both post-g_gemm, independent).
//  blocks [0,512)   : h_qk/h_v reduction from G
//  blocks [512,1024): W_O fp32 -> bf16 into wob (dead-xb region)
// ---------------------------------------------------------------------------
__global__ __launch_bounds__(256) void reduce_h_wo(
    const u16* __restrict__ G, const float* __restrict__ fqk_w,
    const float* __restrict__ fv_w, float* __restrict__ h_qk,
    float* __restrict__ h_v, const float* __restrict__ WO,
    u16* __restrict__ wob) {
  const int bx = blockIdx.x;
  if (bx < 512) {                                // ---- reduce_h ----
    int idx = bx * 256 + threadIdx.x;            // 0..131071
    int t = idx >> 4, r4 = (idx & 15) * 4;
    float4 aq = {0.f, 0.f, 0.f, 0.f}, av = {0.f, 0.f, 0.f, 0.f};
    const u16* gq = &G[(size_t)t * 4096 + r4];
    const u16* gv = gq + 2048;
#pragma unroll 4
    for (int n = 0; n < 32; ++n) {
      float wa = fqk_w[t * 32 + n];
      float wb = fv_w[t * 32 + n];
      ushort4 g1 = *(const ushort4*)&gq[n * 64];
      ushort4 g2 = *(const ushort4*)&gv[n * 64];
      aq.x += wa * bf2f(g1.x); aq.y += wa * bf2f(g1.y);
      aq.z += wa * bf2f(g1.z); aq.w += wa * bf2f(g1.w);
      av.x += wb * bf2f(g2.x); av.y += wb * bf2f(g2.y);
      av.z += wb * bf2f(g2.z); av.w += wb * bf2f(g2.w);
    }
    *(float4*)&h_qk[t * 64 + r4] = aq;
    *(float4*)&h_v[t * 64 + r4] = av;
  } else {                                       // ---- conv_wo ----
    int idx = (bx - 512) * 256 + threadIdx.x;
    float4 v0 = ((const float4*)WO)[idx * 2];
    float4 v1 = ((const float4*)WO)[idx * 2 + 1];
    uint4 o = { pk_bf16(v0.x, v0.y), pk_bf16(v0.z, v0.w),
                pk_bf16(v1.x, v1.y), pk_bf16(v1.z, v1.w) };
    ((uint4*)wob)[idx] = o;
  }
}

// ---------------------------------------------------------------------------
// QKV-GEMM: round-19 32x128 wave retile (frozen best: 125us).
// which: 0->Qb (bf16, [t][d]), 1->Kb (bf16, [t][d]), 2->VTg ([b][h][d][s]).
// ---------------------------------------------------------------------------
__global__ __launch_bounds__(256) void qkv_gemm(
    const float* __restrict__ h_qk, const float* __restrict__ h_v,
    const float* __restrict__ wq, const float* __restrict__ wk,
    const float* __restrict__ wv, const u16* __restrict__ RT,
    u16* __restrict__ Qb, u16* __restrict__ Kb, u16* __restrict__ VTg) {
  __shared__ float hs[128 * 68];                 // aliased by Bs after hoist
  __shared__ float wsl[128 * 33];
  short* Bs = (short*)hs;                        // needs 128*64*2 = 16 KB
  const int tid = threadIdx.x;
  const int lane = tid & 63, wid = tid >> 6;     // wid 0..3 = M-strip of 32
  const int quad = lane >> 4, l15 = lane & 15;
  const int dT = blockIdx.x * 128;
  const int tok0 = blockIdx.y * 128;
  const int which = blockIdx.z;
  const float* __restrict__ h = (which == 2) ? h_v : h_qk;
  const float* __restrict__ w = (which == 0) ? wq : (which == 1) ? wk : wv;
  const int g0 = (which == 2) ? 2048 : 0;

#pragma unroll
  for (int e = 0; e < 8; ++e) {                  // h tile: 128x64 fp32
    int flat = tid + e * 256;                    // 0..2047 (float4 units)
    int row = flat >> 4, rq = (flat & 15) * 4;
    *(float4*)&hs[row * 68 + rq] =
        *(const float4*)&h[(size_t)(tok0 + row) * 64 + rq];
  }
#pragma unroll
  for (int e = 0; e < 16; ++e) {                 // w tile: 128x32 fp32
    int flat = tid + e * 256;                    // 0..4095
    int row = flat >> 5, nn = flat & 31;
    wsl[row * 33 + nn] = w[(size_t)(tok0 + row) * 32 + nn];
  }
  __syncthreads();

  f32x4 hreg[2][4];
#pragma unroll
  for (int mt = 0; mt < 2; ++mt) {
    const float* hp = &hs[(wid * 32 + mt * 16 + l15) * 68 + quad * 8];
    hreg[mt][0] = *(const f32x4*)hp;
    hreg[mt][1] = *(const f32x4*)(hp + 4);
    hreg[mt][2] = *(const f32x4*)(hp + 32);
    hreg[mt][3] = *(const f32x4*)(hp + 36);
  }

  f32x4 acc[2][8];
#pragma unroll
  for (int mt = 0; mt < 2; ++mt)
#pragma unroll
    for (int nt = 0; nt < 8; ++nt) acc[mt][nt] = {0.f, 0.f, 0.f, 0.f};

#pragma unroll 1
  for (int n = 0; n < 32; ++n) {
    __syncthreads();                             // hs reads done / prev iter
#pragma unroll
    for (int e = 0; e < 4; ++e) {                // B: 128x64, DMA swizzled
      int flat = tid + e * 256;                  // 0..1023 (16B units)
      int r = flat >> 3, u = (flat & 7) ^ (r & 7);
      gl_lds16(&RT[(size_t)(dT + r) * 4096 + g0 + n * 64 + u * 8],
               &Bs[flat * 8]);
    }
    __syncthreads();
    s8v a0[2], a1[2], b0[8], b1[8];
#pragma unroll
    for (int mt = 0; mt < 2; ++mt) {
      float wv_ = wsl[(wid * 32 + mt * 16 + l15) * 33 + n];
      f32x2 w2 = {wv_, wv_};
      F4U h0, h1, h2, h3;
      h0.v = hreg[mt][0]; h1.v = hreg[mt][1];
      h2.v = hreg[mt][2]; h3.v = hreg[mt][3];
      f32x2 a00 = w2 * h0.p[0], a01 = w2 * h0.p[1];
      f32x2 a10 = w2 * h1.p[0], a11 = w2 * h1.p[1];
      f32x2 a20 = w2 * h2.p[0], a21 = w2 * h2.p[1];
      f32x2 a30 = w2 * h3.p[0], a31 = w2 * h3.p[1];
      FragU fa, fb;
      fa.u[0] = pk_bf16(a00[0], a00[1]);
      fa.u[1] = pk_bf16(a01[0], a01[1]);
      fa.u[2] = pk_bf16(a10[0], a10[1]);
      fa.u[3] = pk_bf16(a11[0], a11[1]);
      a0[mt] = fa.s;
      fb.u[0] = pk_bf16(a20[0], a20[1]);
      fb.u[1] = pk_bf16(a21[0], a21[1]);
      fb.u[2] = pk_bf16(a30[0], a30[1]);
      fb.u[3] = pk_bf16(a31[0], a31[1]);
      a1[mt] = fb.s;
    }
#pragma unroll
    for (int nt = 0; nt < 8; ++nt) {
      int r = nt * 16 + l15;
      b0[nt] = *(const s8v*)&Bs[r * 64 + ((quad) ^ (r & 7)) * 8];
      b1[nt] = *(const s8v*)&Bs[r * 64 + ((4 + quad) ^ (r & 7)) * 8];
    }
#pragma unroll
    for (int mt = 0; mt < 2; ++mt)
#pragma unroll
      for (int nt = 0; nt < 8; ++nt) {
        acc[mt][nt] = __builtin_amdgcn_mfma_f32_16x16x32_bf16(
            a0[mt], b0[nt], acc[mt][nt], 0, 0, 0);
        acc[mt][nt] = __builtin_amdgcn_mfma_f32_16x16x32_bf16(
            a1[mt], b1[nt], acc[mt][nt], 0, 0, 0);
      }
  }

  if (which < 2) {
    u16* __restrict__ O = (which == 0) ? Qb : Kb;
#pragma unroll
    for (int mt = 0; mt < 2; ++mt)
#pragma unroll
      for (int nt = 0; nt < 8; ++nt) {
        int col = dT + nt * 16 + l15;
        int rbase = tok0 + wid * 32 + mt * 16 + quad * 4;
#pragma unroll
        for (int i = 0; i < 4; ++i)
          O[(size_t)(rbase + i) * kD + col] = f2bf_bits(acc[mt][nt][i]);
      }
  } else {
#pragma unroll
    for (int mt = 0; mt < 2; ++mt)
#pragma unroll
      for (int nt = 0; nt < 8; ++nt) {
        int d = dT + nt * 16 + l15;
        int hh = d >> 6, dl = d & 63;
        int t = tok0 + wid * 32 + mt * 16 + quad * 4;  // 4 consecutive tokens
        int bb = t >> 11, sl = t & 2047;
        ushort4 u = { f2bf_bits(acc[mt][nt][0]), f2bf_bits(acc[mt][nt][1]),
                      f2bf_bits(acc[mt][nt][2]), f2bf_bits(acc[mt][nt][3]) };
        *(ushort4*)&VTg[(((size_t)bb * 16 + hh) * 64 + dl) * kS + sl] = u;
      }
  }
}

// ---------------------------------------------------------------------------
// Flash attention, transposed-score MFMA.
// Round 20: round-12 structure + s_setprio(1) around the two MFMA clusters
// (isolated; post-r12 mixed-qb co-residency = m191's favorable regime).
// ---------------------------------------------------------------------------
__global__ __launch_bounds__(512) void attn_mfma(
    const u16* __restrict__ Qb, const u16* __restrict__ Kb,
    const u16* __restrict__ VTg, u16* __restrict__ AOb)
{
  __shared__ short Ks[64 * 72];       // [k-tok][d]
  __shared__ short VTs[64 * 72];      // [d][k-tok]
  __shared__ short Ps[8][16 * 72];    // per-wave P strip [q-local][k-tok]
  const int tid = threadIdx.x;
  const int lane = tid & 63, w = tid >> 6;       // w 0..7
  const int quad = lane >> 4, l15 = lane & 15;
  const int qb = (blockIdx.x + blockIdx.y + 4 * blockIdx.z) & 15;
  const int hh = blockIdx.y, b = blockIdx.z;
  const int dh = hh * 64;
  const size_t qrow0 = (size_t)b * kS + (size_t)qb * 128;
  const int ktmax = qb * 2 + 1;
  const u16* __restrict__ vbase = VTg + ((size_t)(b * 16 + hh) * 64) * kS;

  const int prow = tid >> 3;                     // 0..63
  const int pd8  = (tid & 7) * 8;                // 16B staging mapping

  *(uint4*)&Ks[prow * 72 + pd8] =
      *(const uint4*)&Kb[((size_t)b * kS + prow) * kD + dh + pd8];
  *(uint4*)&VTs[prow * 72 + pd8] =
      *(const uint4*)&vbase[(size_t)prow * kS + pd8];

  // Q fragments: one-time per-wave direct global load
  const size_t qrow = qrow0 + w * 16 + l15;
  s8v bq0 = *(const s8v*)&Qb[qrow * kD + dh + quad * 8];
  s8v bq1 = *(const s8v*)&Qb[qrow * kD + dh + 32 + quad * 8];
  __syncthreads();

  const int q_g = qb * 128 + w * 16 + l15;
  const int qmax_w = qb * 128 + w * 16 + 15;
  float m = -INFINITY, l = 0.f;
  f32x4 O[4];
#pragma unroll
  for (int dt = 0; dt < 4; ++dt) O[dt] = {0.f, 0.f, 0.f, 0.f};

#pragma unroll 1
  for (int kt = 0; kt <= ktmax; ++kt) {
    uint4 pk, pv;
    if (kt < ktmax) {
      const size_t krn = (size_t)b * kS + (size_t)(kt + 1) * 64;
      pk = *(const uint4*)&Kb[(krn + prow) * kD + dh + pd8];
      pv = *(const uint4*)&vbase[(size_t)prow * kS + (kt + 1) * 64 + pd8];
    }

    if (kt * 64 <= qmax_w) {
      f32x4 st[4];
      __builtin_amdgcn_s_setprio(1);
#pragma unroll
      for (int nt = 0; nt < 4; ++nt) {
        const short* p = &Ks[(nt * 16 + l15) * 72 + quad * 8];
        s8v ak0 = *(const s8v*)p;
        s8v ak1 = *(const s8v*)(p + 32);
        f32x4 z = {0.f, 0.f, 0.f, 0.f};
        z = __builtin_amdgcn_mfma_f32_16x16x32_bf16(ak0, bq0, z, 0, 0, 0);
        st[nt] = __builtin_amdgcn_mfma_f32_16x16x32_bf16(ak1, bq1, z, 0, 0, 0);
      }
      __builtin_amdgcn_s_setprio(0);

      if (kt * 64 + 63 > qb * 128 + w * 16) {
#pragma unroll
        for (int nt = 0; nt < 4; ++nt)
#pragma unroll
          for (int i = 0; i < 4; ++i)
            if (kt * 64 + nt * 16 + quad * 4 + i > q_g) st[nt][i] = -1e30f;
      }

      float pm = -INFINITY;
#pragma unroll
      for (int nt = 0; nt < 4; ++nt)
#pragma unroll
        for (int i = 0; i < 4; ++i) pm = fmaxf(pm, st[nt][i]);
      pm = fmaxf(pm, __shfl_xor(pm, 16, 64));
      pm = fmaxf(pm, __shfl_xor(pm, 32, 64));
      float mn = fmaxf(m, pm);
      float alpha = __expf((m - mn) * 0.125f);
      m = mn;
      float p[4][4];
      float r = 0.f;
#pragma unroll
      for (int nt = 0; nt < 4; ++nt)
#pragma unroll
        for (int i = 0; i < 4; ++i) {
          p[nt][i] = __expf((st[nt][i] - mn) * 0.125f);
          r += p[nt][i];
        }
      r += __shfl_xor(r, 16, 64);
      r += __shfl_xor(r, 32, 64);
      l = l * alpha + r;
#pragma unroll
      for (int dt = 0; dt < 4; ++dt)
#pragma unroll
        for (int i = 0; i < 4; ++i) O[dt][i] *= alpha;

#pragma unroll
      for (int nt = 0; nt < 4; ++nt) {
        uint2 o = { pk_bf16(p[nt][0], p[nt][1]), pk_bf16(p[nt][2], p[nt][3]) };
        *(uint2*)&Ps[w][l15 * 72 + nt * 16 + quad * 4] = o;
      }
      s8v bp0 = *(const s8v*)&Ps[w][l15 * 72 + quad * 8];
      s8v bp1 = *(const s8v*)&Ps[w][l15 * 72 + 32 + quad * 8];
      __builtin_amdgcn_s_setprio(1);
#pragma unroll
      for (int dt = 0; dt < 4; ++dt) {
        const short* p2 = &VTs[(dt * 16 + l15) * 72 + quad * 8];
        s8v av0 = *(const s8v*)p2;
        s8v av1 = *(const s8v*)(p2 + 32);
        O[dt] = __builtin_amdgcn_mfma_f32_16x16x32_bf16(av0, bp0, O[dt], 0, 0, 0);
        O[dt] = __builtin_amdgcn_mfma_f32_16x16x32_bf16(av1, bp1, O[dt], 0, 0, 0);
      }
      __builtin_amdgcn_s_setprio(0);
    }

    __syncthreads();
    if (kt < ktmax) {
      *(uint4*)&Ks[prow * 72 + pd8] = pk;
      *(uint4*)&VTs[prow * 72 + pd8] = pv;
    }
    __syncthreads();
  }

  const float inv = 1.f / l;
  const size_t row = qrow0 + w * 16 + l15;
#pragma unroll
  for (int dt = 0; dt < 4; ++dt) {
    uint2 o = { pk_bf16(O[dt][0] * inv, O[dt][1] * inv),
                pk_bf16(O[dt][2] * inv, O[dt][3] * inv) };
    *(uint2*)&AOb[row * kD + dh + dt * 16 + quad * 4] = o;
  }
}

// ---------------------------------------------------------------------------
// WO-GEMM: out[t][d] = sum_e AO[t][e] * wob[d][e].  All-bf16, BK=64,
// global_load_lds swizzled staging for both operands.
// ---------------------------------------------------------------------------
__global__ __launch_bounds__(256) void wo_gemm(const u16* __restrict__ AOb,
                                               const u16* __restrict__ wob,
                                               float* __restrict__ out) {
  __shared__ short As[128 * 64];
  __shared__ short Bs[128 * 64];
  const int tid = threadIdx.x;
  const int lane = tid & 63, wid = tid >> 6;
  const int wm = wid & 1, wn = wid >> 1;
  const int quad = lane >> 4, l15 = lane & 15;
  const int dT = blockIdx.x * 128;
  const int tok0 = blockIdx.y * 128;

  f32x4 acc[4][4];
#pragma unroll
  for (int mt = 0; mt < 4; ++mt)
#pragma unroll
    for (int nt = 0; nt < 4; ++nt) acc[mt][nt] = {0.f, 0.f, 0.f, 0.f};

#pragma unroll 1
  for (int e0 = 0; e0 < kD; e0 += 64) {
    __syncthreads();
#pragma unroll
    for (int e = 0; e < 4; ++e) {                 // A: AO, DMA swizzled
      int flat = tid + e * 256;
      int r = flat >> 3, u = (flat & 7) ^ (r & 7);
      gl_lds16(&AOb[(size_t)(tok0 + r) * kD + e0 + u * 8], &As[flat * 8]);
    }
#pragma unroll
    for (int e = 0; e < 4; ++e) {                 // B: wob, DMA swizzled
      int flat = tid + e * 256;
      int r = flat >> 3, u = (flat & 7) ^ (r & 7);
      gl_lds16(&wob[(size_t)(dT + r) * kD + e0 + u * 8], &Bs[flat * 8]);
    }
    __syncthreads();
    s8v a0[4], a1[4], b0[4], b1[4];
#pragma unroll
    for (int mt = 0; mt < 4; ++mt) {
      int r = wm * 64 + mt * 16 + l15;
      a0[mt] = *(const s8v*)&As[r * 64 + ((quad) ^ (r & 7)) * 8];
      a1[mt] = *(const s8v*)&As[r * 64 + ((4 + quad) ^ (r & 7)) * 8];
    }
#pragma unroll
    for (int nt = 0; nt < 4; ++nt) {
      int r = wn * 64 + nt * 16 + l15;
      b0[nt] = *(const s8v*)&Bs[r * 64 + ((quad) ^ (r & 7)) * 8];
      b1[nt] = *(const s8v*)&Bs[r * 64 + ((4 + quad) ^ (r & 7)) * 8];
    }
#pragma unroll
    for (int mt = 0; mt < 4; ++mt)
#pragma unroll
      for (int nt = 0; nt < 4; ++nt) {
        acc[mt][nt] = __builtin_amdgcn_mfma_f32_16x16x32_bf16(
            a0[mt], b0[nt], acc[mt][nt], 0, 0, 0);
        acc[mt][nt] = __builtin_amdgcn_mfma_f32_16x16x32_bf16(
            a1[mt], b1[nt], acc[mt][nt], 0, 0, 0);
      }
  }
#pragma unroll
  for (int mt = 0; mt < 4; ++mt)
#pragma unroll
    for (int nt = 0; nt < 4; ++nt) {
      int col = dT + wn * 64 + nt * 16 + l15;
      int rbase = tok0 + wm * 64 + mt * 16 + quad * 4;
#pragma unroll
      for (int i = 0; i < 4; ++i)
        out[(size_t)(rbase + i) * kD + col] = acc[mt][nt][i];
    }
}

// ---------------------------------------------------------------------------
extern "C" void kernel_launch(void* const* d_in, const int* in_sizes, int n_in,
                              void* d_out, int out_size, void* d_ws, size_t ws_size,
                              hipStream_t stream) {
  const float* x     = (const float*)d_in[0];
  const float* fqk_w = (const float*)d_in[1];
  const float* fv_w  = (const float*)d_in[2];
  const float* wq    = (const float*)d_in[3];
  const float* wk    = (const float*)d_in[4];
  const float* wv    = (const float*)d_in[5];
  const float* f_neu = (const float*)d_in[6];
  const float* r_neu = (const float*)d_in[7];
  const float* WO    = (const float*)d_in[8];
  float* out = (float*)d_out;

  // ws layout (100 MB, lifetime-overlapped):
  //  [0,8)    FT (dead after g_gemm)
  //  [8,16)   RT (dead after qkv_gemm)
  //  [16,80)  G  (dead after reduce_h_wo) -> Qb [16,32), Kb [32,48),
  //                                          VTg [48,64), AOb [64,80)
  //  [80,84)  h_qk, h_v
  //  [84,100) xb (bf16 x; dead after g_gemm) -> wob [84,86) (reduce_h_wo)
  char* ws = (char*)d_ws;
  u16*   FT   = (u16*)  (ws);
  u16*   RT   = (u16*)  (ws + ((size_t)8u  << 20));
  u16*   G    = (u16*)  (ws + ((size_t)16u << 20));
  float* h_qk = (float*)(ws + ((size_t)80u << 20));
  float* h_v  = (float*)(ws + ((size_t)82u << 20));
  u16*   Qb   = (u16*)  (ws + ((size_t)16u << 20));
  u16*   Kb   = (u16*)  (ws + ((size_t)32u << 20));
  u16*   VTg  = (u16*)  (ws + ((size_t)48u << 20));
  u16*   AOb  = (u16*)  (ws + ((size_t)64u << 20));
  u16*   xb   = (u16*)  (ws + ((size_t)84u << 20));
  u16*   wob  = (u16*)  (ws + ((size_t)84u << 20));   // reuses dead xb

  hipLaunchKernelGGL(prep, dim3(5120), dim3(256), 0, stream,
                     x, xb, f_neu, FT, r_neu, RT);
  hipLaunchKernelGGL(g_gemm, dim3(32, 64), dim3(256), 0, stream, xb, FT, G);
  hipLaunchKernelGGL(reduce_h_wo, dim3(1024), dim3(256), 0, stream,
                     G, fqk_w, fv_w, h_qk, h_v, WO, wob);
  hipLaunchKernelGGL(qkv_gemm, dim3(8, 64, 3), dim3(256), 0, stream,
                     h_qk, h_v, wq, wk, wv, RT, Qb, Kb, VTg);
  hipLaunchKernelGGL(attn_mfma, dim3(16, 16, 4), dim3(512), 0, stream,
                     Qb, Kb, VTg, AOb);
  hipLaunchKernelGGL(wo_gemm, dim3(8, 64), dim3(256), 0, stream,
                     AOb, wob, out);
}